// Round 1
// baseline (671.371 us; speedup 1.0000x reference)
//
#include <hip/hip_runtime.h>
#include <math.h>

typedef __attribute__((ext_vector_type(8))) short bfrag;   // 8 x bf16 bits
typedef __attribute__((ext_vector_type(4))) float f32x4;   // MFMA accumulator

// ---------- bf16 helpers ----------
__device__ __forceinline__ unsigned short bf16_rne(float f) {
  unsigned int u = __float_as_uint(f);
  u += 0x7FFFu + ((u >> 16) & 1u);
  return (unsigned short)(u >> 16);
}
__device__ __forceinline__ float bf16f(unsigned short h) {
  return __uint_as_float(((unsigned int)h) << 16);
}
// split x into 3 bf16 terms: x ~= o1 + o2 + o3  (rel err ~2^-22)
__device__ __forceinline__ void split3(float x, unsigned short &o1, unsigned short &o2, unsigned short &o3) {
  o1 = bf16_rne(x);
  const float r1 = x - bf16f(o1);
  o2 = bf16_rne(r1);
  const float r2 = r1 - bf16f(o2);
  o3 = bf16_rne(r2);
}

// ---------- LayerNorm (row = 1024 f32) ----------
__global__ __launch_bounds__(256) void ln_kernel(const float* __restrict__ x,
                                                 const float* __restrict__ w,
                                                 float* __restrict__ out) {
  const int t = blockIdx.x;
  const int tid = threadIdx.x;
  const float4 v = *reinterpret_cast<const float4*>(&x[(size_t)t * 1024 + tid * 4]);
  float s = v.x + v.y + v.z + v.w;
  float ss = v.x * v.x + v.y * v.y + v.z * v.z + v.w * v.w;
#pragma unroll
  for (int off = 32; off; off >>= 1) {
    s += __shfl_xor(s, off);
    ss += __shfl_xor(ss, off);
  }
  __shared__ float red1[4], red2[4];
  if ((tid & 63) == 0) { red1[tid >> 6] = s; red2[tid >> 6] = ss; }
  __syncthreads();
  s = red1[0] + red1[1] + red1[2] + red1[3];
  ss = red2[0] + red2[1] + red2[2] + red2[3];
  const float mu = s * (1.0f / 1024.0f);
  const float var = ss * (1.0f / 1024.0f) - mu * mu;
  const float rstd = 1.0f / sqrtf(var + 1e-5f);
  const float4 wv = *reinterpret_cast<const float4*>(&w[tid * 4]);
  float4 o;
  o.x = (v.x - mu) * rstd * wv.x;
  o.y = (v.y - mu) * rstd * wv.y;
  o.z = (v.z - mu) * rstd * wv.z;
  o.w = (v.w - mu) * rstd * wv.w;
  *reinterpret_cast<float4*>(&out[(size_t)t * 1024 + tid * 4]) = o;
}

// ---------- high-precision GEMM: C = [clip]( A(Mx K) @ B(K x N) ) [+ Res]
// 64x64 tile, BK=32, 4 waves of 32x32, split-3 bf16 emulation of fp32.
// grid.x = M/64 (mt), grid.y = N/64 (nt)
__global__ __launch_bounds__(256) void gemm_split3_kernel(
    const float* __restrict__ A, const float* __restrict__ B,
    float* __restrict__ C, const float* __restrict__ Res,
    int N, int K, int doclip) {
  __shared__ alignas(16) unsigned short A1[64][40], A2[64][40], A3[64][40];
  __shared__ alignas(16) unsigned short B1[64][40], B2[64][40], B3[64][40];
  const int tid = threadIdx.x;
  const int m0 = blockIdx.x * 64;
  const int n0 = blockIdx.y * 64;
  const int w = tid >> 6, l = tid & 63;
  const int wm = (w >> 1) * 32, wn = (w & 1) * 32;
  const int lr = l & 15, lg = l >> 4;
  const int tkA = tid & 7, tmA = tid >> 3;
  const int tnB = tid & 63, kbB = tid >> 6;

  f32x4 acc[2][2] = {{{0.f,0.f,0.f,0.f},{0.f,0.f,0.f,0.f}},
                     {{0.f,0.f,0.f,0.f},{0.f,0.f,0.f,0.f}}};

  for (int k0 = 0; k0 < K; k0 += 32) {
#pragma unroll
    for (int p = 0; p < 2; ++p) {
      const int m = tmA + p * 32;
      const float4 va = *reinterpret_cast<const float4*>(&A[(size_t)(m0 + m) * K + k0 + tkA * 4]);
      unsigned short h1[4], h2[4], h3[4];
      split3(va.x, h1[0], h2[0], h3[0]);
      split3(va.y, h1[1], h2[1], h3[1]);
      split3(va.z, h1[2], h2[2], h3[2]);
      split3(va.w, h1[3], h2[3], h3[3]);
      *reinterpret_cast<ushort4*>(&A1[m][tkA * 4]) = make_ushort4(h1[0], h1[1], h1[2], h1[3]);
      *reinterpret_cast<ushort4*>(&A2[m][tkA * 4]) = make_ushort4(h2[0], h2[1], h2[2], h2[3]);
      *reinterpret_cast<ushort4*>(&A3[m][tkA * 4]) = make_ushort4(h3[0], h3[1], h3[2], h3[3]);
    }
    {
      unsigned short b1[8], b2[8], b3[8];
#pragma unroll
      for (int j = 0; j < 8; ++j) {
        const float vb = B[(size_t)(k0 + kbB * 8 + j) * N + n0 + tnB];
        split3(vb, b1[j], b2[j], b3[j]);
      }
      *reinterpret_cast<ushort4*>(&B1[tnB][kbB * 8])     = make_ushort4(b1[0], b1[1], b1[2], b1[3]);
      *reinterpret_cast<ushort4*>(&B1[tnB][kbB * 8 + 4]) = make_ushort4(b1[4], b1[5], b1[6], b1[7]);
      *reinterpret_cast<ushort4*>(&B2[tnB][kbB * 8])     = make_ushort4(b2[0], b2[1], b2[2], b2[3]);
      *reinterpret_cast<ushort4*>(&B2[tnB][kbB * 8 + 4]) = make_ushort4(b2[4], b2[5], b2[6], b2[7]);
      *reinterpret_cast<ushort4*>(&B3[tnB][kbB * 8])     = make_ushort4(b3[0], b3[1], b3[2], b3[3]);
      *reinterpret_cast<ushort4*>(&B3[tnB][kbB * 8 + 4]) = make_ushort4(b3[4], b3[5], b3[6], b3[7]);
    }
    __syncthreads();
    bfrag af[2][3], bg[2][3];
#pragma unroll
    for (int mi = 0; mi < 2; ++mi) {
      const int ar = wm + mi * 16 + lr;
      af[mi][0] = *reinterpret_cast<const bfrag*>(&A1[ar][lg * 8]);
      af[mi][1] = *reinterpret_cast<const bfrag*>(&A2[ar][lg * 8]);
      af[mi][2] = *reinterpret_cast<const bfrag*>(&A3[ar][lg * 8]);
    }
#pragma unroll
    for (int ni = 0; ni < 2; ++ni) {
      const int br = wn + ni * 16 + lr;
      bg[ni][0] = *reinterpret_cast<const bfrag*>(&B1[br][lg * 8]);
      bg[ni][1] = *reinterpret_cast<const bfrag*>(&B2[br][lg * 8]);
      bg[ni][2] = *reinterpret_cast<const bfrag*>(&B3[br][lg * 8]);
    }
#pragma unroll
    for (int mi = 0; mi < 2; ++mi)
#pragma unroll
      for (int ni = 0; ni < 2; ++ni) {
        f32x4 c = acc[mi][ni];
        c = __builtin_amdgcn_mfma_f32_16x16x32_bf16(af[mi][2], bg[ni][0], c, 0, 0, 0);
        c = __builtin_amdgcn_mfma_f32_16x16x32_bf16(af[mi][1], bg[ni][1], c, 0, 0, 0);
        c = __builtin_amdgcn_mfma_f32_16x16x32_bf16(af[mi][0], bg[ni][2], c, 0, 0, 0);
        c = __builtin_amdgcn_mfma_f32_16x16x32_bf16(af[mi][1], bg[ni][0], c, 0, 0, 0);
        c = __builtin_amdgcn_mfma_f32_16x16x32_bf16(af[mi][0], bg[ni][1], c, 0, 0, 0);
        c = __builtin_amdgcn_mfma_f32_16x16x32_bf16(af[mi][0], bg[ni][0], c, 0, 0, 0);
        acc[mi][ni] = c;
      }
    __syncthreads();
  }
#pragma unroll
  for (int mi = 0; mi < 2; ++mi)
#pragma unroll
    for (int ni = 0; ni < 2; ++ni)
#pragma unroll
      for (int r = 0; r < 4; ++r) {
        const int row = m0 + wm + mi * 16 + lg * 4 + r;
        const int col = n0 + wn + ni * 16 + lr;
        float vv = acc[mi][ni][r];
        if (doclip) vv = fminf(fmaxf(vv, -8.0f), 8.0f);
        if (Res) vv += Res[(size_t)row * N + col];
        C[(size_t)row * N + col] = vv;
      }
}

// ---------- RoPE in-place on q (T,16,64) and k (T,4,64), f64 trig ----------
__global__ void rope_kernel(float* __restrict__ q, float* __restrict__ k,
                            const int* __restrict__ posids) {
  const int t = blockIdx.x;
  const int hh = blockIdx.y;   // 0..19: 16 q heads then 4 k heads
  const int i = threadIdx.x;   // 0..31
  float* ptr = (hh < 16) ? &q[((size_t)t * 16 + hh) * 64]
                         : &k[((size_t)t * 4 + (hh - 16)) * 64];
  const double ang = (double)posids[t] * pow(500000.0, -(double)i / 32.0);
  const double c = cos(ang), s = sin(ang);
  const float u1 = ptr[i], u2 = ptr[i + 32];
  ptr[i]      = (float)((double)u1 * c - (double)u2 * s);
  ptr[i + 32] = (float)((double)u2 * c + (double)u1 * s);
}

// ---------- causal GQA flash attention, fp32 vector ----------
// grid: (qt=16, h=16); block 256: thread = (q_local 0..63, kg 0..3)
__global__ __launch_bounds__(256) void attn_kernel(
    const float* __restrict__ q, const float* __restrict__ k,
    const float* __restrict__ v, float* __restrict__ o) {
  const int qt = blockIdx.x;
  const int h = blockIdx.y;
  const int kvh = h >> 2;
  __shared__ float Ks[32][68], Vs[32][68];
  __shared__ float Ps[64][33];
  const int tid = threadIdx.x;
  const int ql = tid >> 2;
  const int kg = tid & 3;
  const int tq = qt * 64 + ql;

  float qr[64];
#pragma unroll
  for (int d4 = 0; d4 < 16; ++d4) {
    const float4 t4 = *reinterpret_cast<const float4*>(&q[((size_t)tq * 16 + h) * 64 + d4 * 4]);
    qr[d4 * 4 + 0] = t4.x * 0.125f;
    qr[d4 * 4 + 1] = t4.y * 0.125f;
    qr[d4 * 4 + 2] = t4.z * 0.125f;
    qr[d4 * 4 + 3] = t4.w * 0.125f;
  }
  float acc[16];
#pragma unroll
  for (int i = 0; i < 16; ++i) acc[i] = 0.f;
  float mrun = -INFINITY, lsum = 0.f;

  const int ntiles = (qt * 64 + 64) >> 5;
  const int sr = tid >> 3;
  const int sc = (tid & 7) * 8;
  for (int ti = 0; ti < ntiles; ++ti) {
    const int s0 = ti * 32;
    const float* ksrc = &k[((size_t)(s0 + sr) * 4 + kvh) * 64 + sc];
    const float* vsrc = &v[((size_t)(s0 + sr) * 4 + kvh) * 64 + sc];
    *reinterpret_cast<float4*>(&Ks[sr][sc])     = *reinterpret_cast<const float4*>(ksrc);
    *reinterpret_cast<float4*>(&Ks[sr][sc + 4]) = *reinterpret_cast<const float4*>(ksrc + 4);
    *reinterpret_cast<float4*>(&Vs[sr][sc])     = *reinterpret_cast<const float4*>(vsrc);
    *reinterpret_cast<float4*>(&Vs[sr][sc + 4]) = *reinterpret_cast<const float4*>(vsrc + 4);
    __syncthreads();

    float sv[8];
#pragma unroll
    for (int j = 0; j < 8; ++j) sv[j] = 0.f;
#pragma unroll
    for (int d4 = 0; d4 < 16; ++d4) {
#pragma unroll
      for (int j = 0; j < 8; ++j) {
        const float4 kk4 = *reinterpret_cast<const float4*>(&Ks[kg * 8 + j][d4 * 4]);
        sv[j] += qr[d4 * 4 + 0] * kk4.x + qr[d4 * 4 + 1] * kk4.y +
                 qr[d4 * 4 + 2] * kk4.z + qr[d4 * 4 + 3] * kk4.w;
      }
    }
    float tmax = -INFINITY;
#pragma unroll
    for (int j = 0; j < 8; ++j) {
      const int sg = s0 + kg * 8 + j;
      sv[j] = (sg <= tq) ? sv[j] : -INFINITY;
      tmax = fmaxf(tmax, sv[j]);
    }
    tmax = fmaxf(tmax, __shfl_xor(tmax, 1));
    tmax = fmaxf(tmax, __shfl_xor(tmax, 2));
    const float mnew = fmaxf(mrun, tmax);
    const float alpha = expf(mrun - mnew);
    float psum = 0.f;
#pragma unroll
    for (int j = 0; j < 8; ++j) {
      const float pv = expf(sv[j] - mnew);
      Ps[ql][kg * 8 + j] = pv;
      psum += pv;
    }
    psum += __shfl_xor(psum, 1);
    psum += __shfl_xor(psum, 2);
    lsum = lsum * alpha + psum;
#pragma unroll
    for (int i = 0; i < 16; ++i) acc[i] *= alpha;
    __syncthreads();
#pragma unroll 4
    for (int sl = 0; sl < 32; ++sl) {
      const float pp = Ps[ql][sl];
      const float4 v0 = *reinterpret_cast<const float4*>(&Vs[sl][kg * 16]);
      const float4 v1 = *reinterpret_cast<const float4*>(&Vs[sl][kg * 16 + 4]);
      const float4 v2 = *reinterpret_cast<const float4*>(&Vs[sl][kg * 16 + 8]);
      const float4 v3 = *reinterpret_cast<const float4*>(&Vs[sl][kg * 16 + 12]);
      acc[0]  += pp * v0.x;  acc[1]  += pp * v0.y;  acc[2]  += pp * v0.z;  acc[3]  += pp * v0.w;
      acc[4]  += pp * v1.x;  acc[5]  += pp * v1.y;  acc[6]  += pp * v1.z;  acc[7]  += pp * v1.w;
      acc[8]  += pp * v2.x;  acc[9]  += pp * v2.y;  acc[10] += pp * v2.z;  acc[11] += pp * v2.w;
      acc[12] += pp * v3.x;  acc[13] += pp * v3.y;  acc[14] += pp * v3.z;  acc[15] += pp * v3.w;
    }
    mrun = mnew;
    __syncthreads();
  }
  const float inv = 1.0f / lsum;
#pragma unroll
  for (int i4 = 0; i4 < 4; ++i4) {
    float4 o4;
    o4.x = acc[i4 * 4 + 0] * inv;
    o4.y = acc[i4 * 4 + 1] * inv;
    o4.z = acc[i4 * 4 + 2] * inv;
    o4.w = acc[i4 * 4 + 3] * inv;
    *reinterpret_cast<float4*>(&o[((size_t)tq * 16 + h) * 64 + kg * 16 + i4 * 4]) = o4;
  }
}

// ---------- router: top-2 of softmax(h2 @ Wr) ----------
__global__ __launch_bounds__(64) void router_kernel(const float* __restrict__ h2,
                                                    const float* __restrict__ Wr,
                                                    int* __restrict__ eidx,
                                                    float* __restrict__ egate) {
  const int t = blockIdx.x;
  const int l = threadIdx.x;
  float p[8];
#pragma unroll
  for (int e = 0; e < 8; ++e) p[e] = 0.f;
  for (int d = l; d < 1024; d += 64) {
    const float x = h2[(size_t)t * 1024 + d];
    const float4 w0 = *reinterpret_cast<const float4*>(&Wr[d * 8]);
    const float4 w1 = *reinterpret_cast<const float4*>(&Wr[d * 8 + 4]);
    p[0] += x * w0.x; p[1] += x * w0.y; p[2] += x * w0.z; p[3] += x * w0.w;
    p[4] += x * w1.x; p[5] += x * w1.y; p[6] += x * w1.z; p[7] += x * w1.w;
  }
#pragma unroll
  for (int off = 32; off; off >>= 1) {
#pragma unroll
    for (int e = 0; e < 8; ++e) p[e] += __shfl_xor(p[e], off);
  }
  if (l == 0) {
    int i0 = 0; float b0 = p[0];
#pragma unroll
    for (int e = 1; e < 8; ++e) if (p[e] > b0) { b0 = p[e]; i0 = e; }
    int i1 = -1; float b1 = -INFINITY;
#pragma unroll
    for (int e = 0; e < 8; ++e) if (e != i0 && p[e] > b1) { b1 = p[e]; i1 = e; }
    const float ex = expf(b1 - b0);
    eidx[t * 2] = i0; eidx[t * 2 + 1] = i1;
    egate[t * 2] = 1.0f / (1.0f + ex);
    egate[t * 2 + 1] = ex / (1.0f + ex);
  }
}

// ---------- dispatch: replicate jnp cumsum slot assignment ----------
__global__ __launch_bounds__(256) void dispatch_kernel(
    const int* __restrict__ eidx, int* __restrict__ cnt,
    int* __restrict__ slot_token, int* __restrict__ entry_slot) {
  __shared__ unsigned char ef[2048];
  __shared__ unsigned short ch[256][8];
  const int tid = threadIdx.x;
  for (int i = tid; i < 2048; i += 256) ef[i] = (unsigned char)eidx[i];
  __syncthreads();
  int loc[8];
#pragma unroll
  for (int e = 0; e < 8; ++e) loc[e] = 0;
  const int base = tid * 8;
  for (int j = 0; j < 8; ++j) {
    const int ee = ef[base + j];
#pragma unroll
    for (int e = 0; e < 8; ++e) loc[e] += (ee == e);
  }
#pragma unroll
  for (int e = 0; e < 8; ++e) ch[tid][e] = (unsigned short)loc[e];
  __syncthreads();
  int pre[8];
#pragma unroll
  for (int e = 0; e < 8; ++e) pre[e] = 0;
  for (int t2 = 0; t2 < tid; ++t2) {
#pragma unroll
    for (int e = 0; e < 8; ++e) pre[e] += ch[t2][e];
  }
  if (tid == 255) {
#pragma unroll
    for (int e = 0; e < 8; ++e) cnt[e] = min(pre[e] + loc[e], 512);
  }
  for (int j = 0; j < 8; ++j) {
    const int i = base + j;
    const int ee = ef[i];
    int slot = 0;
#pragma unroll
    for (int e = 0; e < 8; ++e) {
      if (e == ee) { slot = pre[e]; pre[e] = pre[e] + 1; }
    }
    if (slot < 512) {
      slot_token[ee * 512 + slot] = i >> 1;
      entry_slot[i] = slot;
    } else {
      entry_slot[i] = -1;
    }
  }
}

// ---------- MoE pass 1: act = silu(X@Wg) * (X@Wu), bf16 out ----------
// grid: (mt=8, nt=32, e=8)
__global__ __launch_bounds__(256) void moe_mlp1_kernel(
    const float* __restrict__ h2, const float* __restrict__ Wg,
    const float* __restrict__ Wu, const int* __restrict__ cnt,
    const int* __restrict__ slot_token, unsigned short* __restrict__ act) {
  const int mt = blockIdx.x, nt = blockIdx.y, e = blockIdx.z;
  const int ce = cnt[e];
  if (mt * 64 >= ce) return;
  __shared__ alignas(16) unsigned short As[64][40], Bg[64][40], Bu[64][40];
  const int tid = threadIdx.x;
  const int w = tid >> 6, l = tid & 63;
  const int wm = (w >> 1) * 32, wn = (w & 1) * 32;
  const int lr = l & 15, lg = l >> 4;
  const int tkA = tid & 7, tmA = tid >> 3;
  const int tnB = tid & 63, kbB = tid >> 6;
  const int n0 = nt * 64;
  int tok[2];
#pragma unroll
  for (int p = 0; p < 2; ++p) {
    const int m = mt * 64 + tmA + p * 32;
    tok[p] = (m < ce) ? slot_token[e * 512 + m] : -1;
  }
  const float* WgE = Wg + (size_t)e * 1024 * 2048;
  const float* WuE = Wu + (size_t)e * 1024 * 2048;
  f32x4 accG[2][2] = {{{0.f,0.f,0.f,0.f},{0.f,0.f,0.f,0.f}},
                      {{0.f,0.f,0.f,0.f},{0.f,0.f,0.f,0.f}}};
  f32x4 accU[2][2] = {{{0.f,0.f,0.f,0.f},{0.f,0.f,0.f,0.f}},
                      {{0.f,0.f,0.f,0.f},{0.f,0.f,0.f,0.f}}};
  for (int k0 = 0; k0 < 1024; k0 += 32) {
#pragma unroll
    for (int p = 0; p < 2; ++p) {
      float4 va = make_float4(0.f, 0.f, 0.f, 0.f);
      if (tok[p] >= 0)
        va = *reinterpret_cast<const float4*>(&h2[(size_t)tok[p] * 1024 + k0 + tkA * 4]);
      *reinterpret_cast<ushort4*>(&As[tmA + p * 32][tkA * 4]) =
          make_ushort4(bf16_rne(va.x), bf16_rne(va.y), bf16_rne(va.z), bf16_rne(va.w));
    }
    {
      unsigned short gb[8], ub[8];
#pragma unroll
      for (int j = 0; j < 8; ++j) {
        const size_t off = (size_t)(k0 + kbB * 8 + j) * 2048 + n0 + tnB;
        gb[j] = bf16_rne(WgE[off]);
        ub[j] = bf16_rne(WuE[off]);
      }
      *reinterpret_cast<ushort4*>(&Bg[tnB][kbB * 8])     = make_ushort4(gb[0], gb[1], gb[2], gb[3]);
      *reinterpret_cast<ushort4*>(&Bg[tnB][kbB * 8 + 4]) = make_ushort4(gb[4], gb[5], gb[6], gb[7]);
      *reinterpret_cast<ushort4*>(&Bu[tnB][kbB * 8])     = make_ushort4(ub[0], ub[1], ub[2], ub[3]);
      *reinterpret_cast<ushort4*>(&Bu[tnB][kbB * 8 + 4]) = make_ushort4(ub[4], ub[5], ub[6], ub[7]);
    }
    __syncthreads();
    bfrag av[2], gv[2], uv[2];
#pragma unroll
    for (int mi = 0; mi < 2; ++mi)
      av[mi] = *reinterpret_cast<const bfrag*>(&As[wm + mi * 16 + lr][lg * 8]);
#pragma unroll
    for (int ni = 0; ni < 2; ++ni) {
      gv[ni] = *reinterpret_cast<const bfrag*>(&Bg[wn + ni * 16 + lr][lg * 8]);
      uv[ni] = *reinterpret_cast<const bfrag*>(&Bu[wn + ni * 16 + lr][lg * 8]);
    }
#pragma unroll
    for (int mi = 0; mi < 2; ++mi)
#pragma unroll
      for (int ni = 0; ni < 2; ++ni) {
        accG[mi][ni] = __builtin_amdgcn_mfma_f32_16x16x32_bf16(av[mi], gv[ni], accG[mi][ni], 0, 0, 0);
        accU[mi][ni] = __builtin_amdgcn_mfma_f32_16x16x32_bf16(av[mi], uv[ni], accU[mi][ni], 0, 0, 0);
      }
    __syncthreads();
  }
#pragma unroll
  for (int mi = 0; mi < 2; ++mi)
#pragma unroll
    for (int ni = 0; ni < 2; ++ni)
#pragma unroll
      for (int r = 0; r < 4; ++r) {
        const int m = mt * 64 + wm + mi * 16 + lg * 4 + r;
        if (m < ce) {
          const int col = n0 + wn + ni * 16 + lr;
          const float gg = accG[mi][ni][r];
          const float uu = accU[mi][ni][r];
          const float a = gg / (1.0f + expf(-gg)) * uu;
          act[((size_t)e * 512 + m) * 2048 + col] = bf16_rne(a);
        }
      }
}

// ---------- MoE pass 2: ob = act @ Wd ----------
// grid: (mt=8, nt=16, e=8)
__global__ __launch_bounds__(256) void moe_mlp2_kernel(
    const unsigned short* __restrict__ act, const float* __restrict__ Wd,
    const int* __restrict__ cnt, float* __restrict__ ob) {
  const int mt = blockIdx.x, nt = blockIdx.y, e = blockIdx.z;
  const int ce = cnt[e];
  if (mt * 64 >= ce) return;
  __shared__ alignas(16) unsigned short As[64][40], Bs[64][40];
  const int tid = threadIdx.x;
  const int w = tid >> 6, l = tid & 63;
  const int wm = (w >> 1) * 32, wn = (w & 1) * 32;
  const int lr = l & 15, lg = l >> 4;
  const int tk4 = tid & 3, tmA = tid >> 2;
  const int tnB = tid & 63, kbB = tid >> 6;
  const int n0 = nt * 64;
  const unsigned short* actE = act + (size_t)e * 512 * 2048;
  const float* WdE = Wd + (size_t)e * 2048 * 1024;
  const int mrow = mt * 64 + tmA;
  f32x4 acc[2][2] = {{{0.f,0.f,0.f,0.f},{0.f,0.f,0.f,0.f}},
                     {{0.f,0.f,0.f,0.f},{0.f,0.f,0.f,0.f}}};
  for (int k0 = 0; k0 < 2048; k0 += 32) {
    {
      float4 raw = make_float4(0.f, 0.f, 0.f, 0.f);
      if (mrow < ce)
        raw = *reinterpret_cast<const float4*>(&actE[(size_t)mrow * 2048 + k0 + tk4 * 8]);
      *reinterpret_cast<float4*>(&As[tmA][tk4 * 8]) = raw;
    }
    {
      unsigned short bb[8];
#pragma unroll
      for (int j = 0; j < 8; ++j)
        bb[j] = bf16_rne(WdE[(size_t)(k0 + kbB * 8 + j) * 1024 + n0 + tnB]);
      *reinterpret_cast<ushort4*>(&Bs[tnB][kbB * 8])     = make_ushort4(bb[0], bb[1], bb[2], bb[3]);
      *reinterpret_cast<ushort4*>(&Bs[tnB][kbB * 8 + 4]) = make_ushort4(bb[4], bb[5], bb[6], bb[7]);
    }
    __syncthreads();
    bfrag av[2], bv[2];
#pragma unroll
    for (int mi = 0; mi < 2; ++mi)
      av[mi] = *reinterpret_cast<const bfrag*>(&As[wm + mi * 16 + lr][lg * 8]);
#pragma unroll
    for (int ni = 0; ni < 2; ++ni)
      bv[ni] = *reinterpret_cast<const bfrag*>(&Bs[wn + ni * 16 + lr][lg * 8]);
#pragma unroll
    for (int mi = 0; mi < 2; ++mi)
#pragma unroll
      for (int ni = 0; ni < 2; ++ni)
        acc[mi][ni] = __builtin_amdgcn_mfma_f32_16x16x32_bf16(av[mi], bv[ni], acc[mi][ni], 0, 0, 0);
    __syncthreads();
  }
#pragma unroll
  for (int mi = 0; mi < 2; ++mi)
#pragma unroll
    for (int ni = 0; ni < 2; ++ni)
#pragma unroll
      for (int r = 0; r < 4; ++r) {
        const int m = mt * 64 + wm + mi * 16 + lg * 4 + r;
        if (m < ce) {
          const int col = n0 + wn + ni * 16 + lr;
          ob[((size_t)e * 512 + m) * 1024 + col] = acc[mi][ni][r];
        }
      }
}

// ---------- combine: out += sum_k gate * ob[e_k][slot_k] ----------
__global__ __launch_bounds__(256) void combine_kernel(
    const float* __restrict__ ob, const int* __restrict__ eidx,
    const float* __restrict__ egate, const int* __restrict__ entry_slot,
    float* __restrict__ out) {
  const int t = blockIdx.x;
  const int d = threadIdx.x * 4;
  float4 o4 = *reinterpret_cast<float4*>(&out[(size_t)t * 1024 + d]);
#pragma unroll
  for (int kk = 0; kk < 2; ++kk) {
    const int i = t * 2 + kk;
    const int s = entry_slot[i];
    if (s >= 0) {
      const int e = eidx[i];
      const float g = egate[i];
      const float4 c = *reinterpret_cast<const float4*>(&ob[((size_t)e * 512 + s) * 1024 + d]);
      o4.x += g * c.x; o4.y += g * c.y; o4.z += g * c.z; o4.w += g * c.w;
    }
  }
  *reinterpret_cast<float4*>(&out[(size_t)t * 1024 + d]) = o4;
}

extern "C" void kernel_launch(void* const* d_in, const int* in_sizes, int n_in,
                              void* d_out, int out_size, void* d_ws, size_t ws_size,
                              hipStream_t stream) {
  const float* hidden = (const float*)d_in[0];
  const int* posids  = (const int*)d_in[1];
  const float* ln1w  = (const float*)d_in[2];
  const float* ln2w  = (const float*)d_in[3];
  const float* Wq    = (const float*)d_in[4];
  const float* Wk    = (const float*)d_in[5];
  const float* Wv    = (const float*)d_in[6];
  const float* Wo    = (const float*)d_in[7];
  const float* Wr    = (const float*)d_in[8];
  const float* Wg    = (const float*)d_in[9];
  const float* Wu    = (const float*)d_in[10];
  const float* Wd    = (const float*)d_in[11];
  float* out = (float*)d_out;

  char* p = (char*)d_ws;
  auto alloc = [&](size_t bytes) { char* r = p; p += (bytes + 255) & ~(size_t)255; return r; };
  float* h1   = (float*)alloc((size_t)1024 * 1024 * 4);
  float* qb   = (float*)alloc((size_t)1024 * 1024 * 4);
  float* kb   = (float*)alloc((size_t)1024 * 256 * 4);
  float* vb   = (float*)alloc((size_t)1024 * 256 * 4);
  float* ao   = (float*)alloc((size_t)1024 * 1024 * 4);
  float* h2   = (float*)alloc((size_t)1024 * 1024 * 4);
  unsigned short* act = (unsigned short*)alloc((size_t)8 * 512 * 2048 * 2);
  float* obuf = (float*)alloc((size_t)8 * 512 * 1024 * 4);
  int* eidx   = (int*)alloc(2048 * 4);
  float* egate = (float*)alloc(2048 * 4);
  int* cnt    = (int*)alloc(8 * 4);
  int* slot_token = (int*)alloc((size_t)8 * 512 * 4);
  int* entry_slot = (int*)alloc(2048 * 4);

  ln_kernel<<<1024, 256, 0, stream>>>(hidden, ln1w, h1);
  gemm_split3_kernel<<<dim3(16, 16), 256, 0, stream>>>(h1, Wq, qb, nullptr, 1024, 1024, 1);
  gemm_split3_kernel<<<dim3(16, 4), 256, 0, stream>>>(h1, Wk, kb, nullptr, 256, 1024, 1);
  gemm_split3_kernel<<<dim3(16, 4), 256, 0, stream>>>(h1, Wv, vb, nullptr, 256, 1024, 1);
  rope_kernel<<<dim3(1024, 20), 32, 0, stream>>>(qb, kb, posids);
  attn_kernel<<<dim3(16, 16), 256, 0, stream>>>(qb, kb, vb, ao);
  gemm_split3_kernel<<<dim3(16, 16), 256, 0, stream>>>(ao, Wo, out, hidden, 1024, 1024, 0);
  ln_kernel<<<1024, 256, 0, stream>>>(out, ln2w, h2);
  router_kernel<<<1024, 64, 0, stream>>>(h2, Wr, eidx, egate);
  dispatch_kernel<<<1, 256, 0, stream>>>(eidx, cnt, slot_token, entry_slot);
  moe_mlp1_kernel<<<dim3(8, 32, 8), 256, 0, stream>>>(h2, Wg, Wu, cnt, slot_token, act);
  moe_mlp2_kernel<<<dim3(8, 16, 8), 256, 0, stream>>>(act, Wd, cnt, obuf);
  combine_kernel<<<1024, 256, 0, stream>>>(obuf, eidx, egate, entry_slot, out);
}

// Round 2
// 513.156 us; speedup vs baseline: 1.3083x; 1.3083x over previous
//
#include <hip/hip_runtime.h>
#include <math.h>

typedef __attribute__((ext_vector_type(8))) short bfrag;   // 8 x bf16 bits
typedef __attribute__((ext_vector_type(8))) unsigned short u16x8;
typedef __attribute__((ext_vector_type(4))) float f32x4;   // MFMA accumulator

// ---------- bf16 helpers ----------
__device__ __forceinline__ unsigned short bf16_rne(float f) {
  unsigned int u = __float_as_uint(f);
  u += 0x7FFFu + ((u >> 16) & 1u);
  return (unsigned short)(u >> 16);
}
__device__ __forceinline__ float bf16f(unsigned short h) {
  return __uint_as_float(((unsigned int)h) << 16);
}
// split x into 3 bf16 terms: x ~= o1 + o2 + o3  (rel err ~2^-22)
__device__ __forceinline__ void split3(float x, unsigned short &o1, unsigned short &o2, unsigned short &o3) {
  o1 = bf16_rne(x);
  const float r1 = x - bf16f(o1);
  o2 = bf16_rne(r1);
  const float r2 = r1 - bf16f(o2);
  o3 = bf16_rne(r2);
}
__device__ __forceinline__ void split2(float x, unsigned short &o1, unsigned short &o2) {
  o1 = bf16_rne(x);
  o2 = bf16_rne(x - bf16f(o1));
}

// ---------- LayerNorm (row = 1024 f32) ----------
__global__ __launch_bounds__(256) void ln_kernel(const float* __restrict__ x,
                                                 const float* __restrict__ w,
                                                 float* __restrict__ out) {
  const int t = blockIdx.x;
  const int tid = threadIdx.x;
  const float4 v = *reinterpret_cast<const float4*>(&x[(size_t)t * 1024 + tid * 4]);
  float s = v.x + v.y + v.z + v.w;
  float ss = v.x * v.x + v.y * v.y + v.z * v.z + v.w * v.w;
#pragma unroll
  for (int off = 32; off; off >>= 1) {
    s += __shfl_xor(s, off);
    ss += __shfl_xor(ss, off);
  }
  __shared__ float red1[4], red2[4];
  if ((tid & 63) == 0) { red1[tid >> 6] = s; red2[tid >> 6] = ss; }
  __syncthreads();
  s = red1[0] + red1[1] + red1[2] + red1[3];
  ss = red2[0] + red2[1] + red2[2] + red2[3];
  const float mu = s * (1.0f / 1024.0f);
  const float var = ss * (1.0f / 1024.0f) - mu * mu;
  const float rstd = 1.0f / sqrtf(var + 1e-5f);
  const float4 wv = *reinterpret_cast<const float4*>(&w[tid * 4]);
  float4 o;
  o.x = (v.x - mu) * rstd * wv.x;
  o.y = (v.y - mu) * rstd * wv.y;
  o.z = (v.z - mu) * rstd * wv.z;
  o.w = (v.w - mu) * rstd * wv.w;
  *reinterpret_cast<float4*>(&out[(size_t)t * 1024 + tid * 4]) = o;
}

// ---------- high-precision GEMM: C = [clip]( A(Mx K) @ B(K x N) ) [+ Res]
__global__ __launch_bounds__(256) void gemm_split3_kernel(
    const float* __restrict__ A, const float* __restrict__ B,
    float* __restrict__ C, const float* __restrict__ Res,
    int N, int K, int doclip) {
  __shared__ alignas(16) unsigned short A1[64][40], A2[64][40], A3[64][40];
  __shared__ alignas(16) unsigned short B1[64][40], B2[64][40], B3[64][40];
  const int tid = threadIdx.x;
  const int m0 = blockIdx.x * 64;
  const int n0 = blockIdx.y * 64;
  const int w = tid >> 6, l = tid & 63;
  const int wm = (w >> 1) * 32, wn = (w & 1) * 32;
  const int lr = l & 15, lg = l >> 4;
  const int tkA = tid & 7, tmA = tid >> 3;
  const int tnB = tid & 63, kbB = tid >> 6;

  f32x4 acc[2][2] = {{{0.f,0.f,0.f,0.f},{0.f,0.f,0.f,0.f}},
                     {{0.f,0.f,0.f,0.f},{0.f,0.f,0.f,0.f}}};

  for (int k0 = 0; k0 < K; k0 += 32) {
#pragma unroll
    for (int p = 0; p < 2; ++p) {
      const int m = tmA + p * 32;
      const float4 va = *reinterpret_cast<const float4*>(&A[(size_t)(m0 + m) * K + k0 + tkA * 4]);
      unsigned short h1[4], h2[4], h3[4];
      split3(va.x, h1[0], h2[0], h3[0]);
      split3(va.y, h1[1], h2[1], h3[1]);
      split3(va.z, h1[2], h2[2], h3[2]);
      split3(va.w, h1[3], h2[3], h3[3]);
      *reinterpret_cast<ushort4*>(&A1[m][tkA * 4]) = make_ushort4(h1[0], h1[1], h1[2], h1[3]);
      *reinterpret_cast<ushort4*>(&A2[m][tkA * 4]) = make_ushort4(h2[0], h2[1], h2[2], h2[3]);
      *reinterpret_cast<ushort4*>(&A3[m][tkA * 4]) = make_ushort4(h3[0], h3[1], h3[2], h3[3]);
    }
    {
      unsigned short b1[8], b2[8], b3[8];
#pragma unroll
      for (int j = 0; j < 8; ++j) {
        const float vb = B[(size_t)(k0 + kbB * 8 + j) * N + n0 + tnB];
        split3(vb, b1[j], b2[j], b3[j]);
      }
      *reinterpret_cast<ushort4*>(&B1[tnB][kbB * 8])     = make_ushort4(b1[0], b1[1], b1[2], b1[3]);
      *reinterpret_cast<ushort4*>(&B1[tnB][kbB * 8 + 4]) = make_ushort4(b1[4], b1[5], b1[6], b1[7]);
      *reinterpret_cast<ushort4*>(&B2[tnB][kbB * 8])     = make_ushort4(b2[0], b2[1], b2[2], b2[3]);
      *reinterpret_cast<ushort4*>(&B2[tnB][kbB * 8 + 4]) = make_ushort4(b2[4], b2[5], b2[6], b2[7]);
      *reinterpret_cast<ushort4*>(&B3[tnB][kbB * 8])     = make_ushort4(b3[0], b3[1], b3[2], b3[3]);
      *reinterpret_cast<ushort4*>(&B3[tnB][kbB * 8 + 4]) = make_ushort4(b3[4], b3[5], b3[6], b3[7]);
    }
    __syncthreads();
    bfrag af[2][3], bg[2][3];
#pragma unroll
    for (int mi = 0; mi < 2; ++mi) {
      const int ar = wm + mi * 16 + lr;
      af[mi][0] = *reinterpret_cast<const bfrag*>(&A1[ar][lg * 8]);
      af[mi][1] = *reinterpret_cast<const bfrag*>(&A2[ar][lg * 8]);
      af[mi][2] = *reinterpret_cast<const bfrag*>(&A3[ar][lg * 8]);
    }
#pragma unroll
    for (int ni = 0; ni < 2; ++ni) {
      const int br = wn + ni * 16 + lr;
      bg[ni][0] = *reinterpret_cast<const bfrag*>(&B1[br][lg * 8]);
      bg[ni][1] = *reinterpret_cast<const bfrag*>(&B2[br][lg * 8]);
      bg[ni][2] = *reinterpret_cast<const bfrag*>(&B3[br][lg * 8]);
    }
#pragma unroll
    for (int mi = 0; mi < 2; ++mi)
#pragma unroll
      for (int ni = 0; ni < 2; ++ni) {
        f32x4 c = acc[mi][ni];
        c = __builtin_amdgcn_mfma_f32_16x16x32_bf16(af[mi][2], bg[ni][0], c, 0, 0, 0);
        c = __builtin_amdgcn_mfma_f32_16x16x32_bf16(af[mi][1], bg[ni][1], c, 0, 0, 0);
        c = __builtin_amdgcn_mfma_f32_16x16x32_bf16(af[mi][0], bg[ni][2], c, 0, 0, 0);
        c = __builtin_amdgcn_mfma_f32_16x16x32_bf16(af[mi][1], bg[ni][0], c, 0, 0, 0);
        c = __builtin_amdgcn_mfma_f32_16x16x32_bf16(af[mi][0], bg[ni][1], c, 0, 0, 0);
        c = __builtin_amdgcn_mfma_f32_16x16x32_bf16(af[mi][0], bg[ni][0], c, 0, 0, 0);
        acc[mi][ni] = c;
      }
    __syncthreads();
  }
#pragma unroll
  for (int mi = 0; mi < 2; ++mi)
#pragma unroll
    for (int ni = 0; ni < 2; ++ni)
#pragma unroll
      for (int r = 0; r < 4; ++r) {
        const int row = m0 + wm + mi * 16 + lg * 4 + r;
        const int col = n0 + wn + ni * 16 + lr;
        float vv = acc[mi][ni][r];
        if (doclip) vv = fminf(fmaxf(vv, -8.0f), 8.0f);
        if (Res) vv += Res[(size_t)row * N + col];
        C[(size_t)row * N + col] = vv;
      }
}

// ---------- RoPE table (f64 trig, computed once) ----------
__global__ void rope_table_kernel(const int* __restrict__ posids,
                                  float* __restrict__ cosT, float* __restrict__ sinT) {
  const int t = blockIdx.x * 8 + (threadIdx.x >> 5);
  const int i = threadIdx.x & 31;
  const double ang = (double)posids[t] * pow(500000.0, -(double)i / 32.0);
  cosT[t * 32 + i] = (float)cos(ang);
  sinT[t * 32 + i] = (float)sin(ang);
}

// ---------- RoPE apply on q (T,16,64) and k (T,4,64) ----------
__global__ void rope_kernel(float* __restrict__ q, float* __restrict__ k,
                            const float* __restrict__ cosT, const float* __restrict__ sinT) {
  const int t = blockIdx.x;
  const int hh = blockIdx.y;   // 0..19: 16 q heads then 4 k heads
  const int i = threadIdx.x;   // 0..31
  float* ptr = (hh < 16) ? &q[((size_t)t * 16 + hh) * 64]
                         : &k[((size_t)t * 4 + (hh - 16)) * 64];
  const float c = cosT[t * 32 + i], s = sinT[t * 32 + i];
  const float u1 = ptr[i], u2 = ptr[i + 32];
  ptr[i]      = u1 * c - u2 * s;
  ptr[i + 32] = u2 * c + u1 * s;
}

// ---------- prep: split-2 bf16 K (row-major) and V (transposed) ----------
__global__ __launch_bounds__(256) void prep_kv_kernel(
    const float* __restrict__ k, const float* __restrict__ v,
    unsigned short* __restrict__ Kp1, unsigned short* __restrict__ Kp2,
    unsigned short* __restrict__ Vp1, unsigned short* __restrict__ Vp2) {
  const int key = blockIdx.x;          // 0..1023
  const int kvh = threadIdx.x >> 6;    // 0..3
  const int d = threadIdx.x & 63;
  const float kk = k[((size_t)key * 4 + kvh) * 64 + d];
  const float vv = v[((size_t)key * 4 + kvh) * 64 + d];
  unsigned short a1, a2, b1, b2;
  split2(kk, a1, a2);
  split2(vv, b1, b2);
  const size_t ki = ((size_t)kvh * 1024 + key) * 64 + d;
  Kp1[ki] = a1; Kp2[ki] = a2;
  const size_t vi = ((size_t)kvh * 64 + d) * 1024 + key;
  Vp1[vi] = b1; Vp2[vi] = b2;
}

// ---------- causal GQA flash attention, split-2 bf16 MFMA ----------
// grid (qt=16, h=16); block 256 = 4 waves x 16 q-rows
__global__ __launch_bounds__(256) void attn_kernel(
    const float* __restrict__ q,
    const unsigned short* __restrict__ Kp1, const unsigned short* __restrict__ Kp2,
    const unsigned short* __restrict__ Vp1, const unsigned short* __restrict__ Vp2,
    float* __restrict__ o) {
  const int qt = blockIdx.x, h = blockIdx.y, kvh = h >> 2;
  __shared__ unsigned short Ks1[64][72], Ks2[64][72], Vt1[64][72], Vt2[64][72];
  __shared__ unsigned short Ps1[4][16][72], Ps2[4][16][72];
  const int tid = threadIdx.x;
  const int w = tid >> 6, l = tid & 63;
  const int lr = l & 15, lg = l >> 4;

  // Q A-fragments (row m = lr, k-dim = head dim), scaled by 1/sqrt(64)
  bfrag aq1[2], aq2[2];
  {
    const int tq = qt * 64 + w * 16 + lr;
    const float* qrow = &q[((size_t)tq * 16 + h) * 64];
#pragma unroll
    for (int ks = 0; ks < 2; ++ks) {
      const int d0 = ks * 32 + lg * 8;
      const float4 f0 = *reinterpret_cast<const float4*>(qrow + d0);
      const float4 f1 = *reinterpret_cast<const float4*>(qrow + d0 + 4);
      const float xv[8] = {f0.x, f0.y, f0.z, f0.w, f1.x, f1.y, f1.z, f1.w};
#pragma unroll
      for (int j = 0; j < 8; ++j) {
        const float xs = xv[j] * 0.125f;
        unsigned short p1, p2;
        split2(xs, p1, p2);
        aq1[ks][j] = (short)p1;
        aq2[ks][j] = (short)p2;
      }
    }
  }

  f32x4 accO[4] = {{0.f,0.f,0.f,0.f},{0.f,0.f,0.f,0.f},{0.f,0.f,0.f,0.f},{0.f,0.f,0.f,0.f}};
  float mrun[4] = {-INFINITY, -INFINITY, -INFINITY, -INFINITY};
  float lrun[4] = {0.f, 0.f, 0.f, 0.f};

  for (int ti = 0; ti <= qt; ++ti) {
    const int s0 = ti * 64;
    // ---- stage K tile [key][d] and V tile transposed [d][key] ----
    {
      const size_t kbase = ((size_t)kvh * 1024 + s0 + l) * 64 + w * 16;
      *reinterpret_cast<u16x8*>(&Ks1[l][w * 16])     = *reinterpret_cast<const u16x8*>(&Kp1[kbase]);
      *reinterpret_cast<u16x8*>(&Ks1[l][w * 16 + 8]) = *reinterpret_cast<const u16x8*>(&Kp1[kbase + 8]);
      *reinterpret_cast<u16x8*>(&Ks2[l][w * 16])     = *reinterpret_cast<const u16x8*>(&Kp2[kbase]);
      *reinterpret_cast<u16x8*>(&Ks2[l][w * 16 + 8]) = *reinterpret_cast<const u16x8*>(&Kp2[kbase + 8]);
      const size_t vbase = ((size_t)kvh * 64 + l) * 1024 + s0 + w * 16;
      *reinterpret_cast<u16x8*>(&Vt1[l][w * 16])     = *reinterpret_cast<const u16x8*>(&Vp1[vbase]);
      *reinterpret_cast<u16x8*>(&Vt1[l][w * 16 + 8]) = *reinterpret_cast<const u16x8*>(&Vp1[vbase + 8]);
      *reinterpret_cast<u16x8*>(&Vt2[l][w * 16])     = *reinterpret_cast<const u16x8*>(&Vp2[vbase]);
      *reinterpret_cast<u16x8*>(&Vt2[l][w * 16 + 8]) = *reinterpret_cast<const u16x8*>(&Vp2[vbase + 8]);
    }
    __syncthreads();

    // ---- S = Q @ K^T (split-2: a1b1 + a1b2 + a2b1) ----
    f32x4 accS[4] = {{0.f,0.f,0.f,0.f},{0.f,0.f,0.f,0.f},{0.f,0.f,0.f,0.f},{0.f,0.f,0.f,0.f}};
#pragma unroll
    for (int ks = 0; ks < 2; ++ks) {
      const int koff = ks * 32 + lg * 8;
#pragma unroll
      for (int ni = 0; ni < 4; ++ni) {
        const bfrag b1 = *reinterpret_cast<const bfrag*>(&Ks1[ni * 16 + lr][koff]);
        const bfrag b2 = *reinterpret_cast<const bfrag*>(&Ks2[ni * 16 + lr][koff]);
        f32x4 c = accS[ni];
        c = __builtin_amdgcn_mfma_f32_16x16x32_bf16(aq1[ks], b2, c, 0, 0, 0);
        c = __builtin_amdgcn_mfma_f32_16x16x32_bf16(aq2[ks], b1, c, 0, 0, 0);
        c = __builtin_amdgcn_mfma_f32_16x16x32_bf16(aq1[ks], b1, c, 0, 0, 0);
        accS[ni] = c;
      }
    }
    // ---- causal mask (diagonal tile only) ----
    if (ti == qt) {
      const int rowb = w * 16 + lg * 4;
#pragma unroll
      for (int ni = 0; ni < 4; ++ni)
#pragma unroll
        for (int r = 0; r < 4; ++r)
          if (ni * 16 + lr > rowb + r) accS[ni][r] = -INFINITY;
    }
    // ---- online softmax ----
    float alpha[4];
#pragma unroll
    for (int r = 0; r < 4; ++r) {
      float tm = fmaxf(fmaxf(accS[0][r], accS[1][r]), fmaxf(accS[2][r], accS[3][r]));
      tm = fmaxf(tm, __shfl_xor(tm, 1));
      tm = fmaxf(tm, __shfl_xor(tm, 2));
      tm = fmaxf(tm, __shfl_xor(tm, 4));
      tm = fmaxf(tm, __shfl_xor(tm, 8));
      const float mnew = fmaxf(mrun[r], tm);
      alpha[r] = __expf(mrun[r] - mnew);
      mrun[r] = mnew;
      float ps = 0.f;
#pragma unroll
      for (int ni = 0; ni < 4; ++ni) {
        const float pv = __expf(accS[ni][r] - mnew);
        accS[ni][r] = pv;
        ps += pv;
      }
      ps += __shfl_xor(ps, 1);
      ps += __shfl_xor(ps, 2);
      ps += __shfl_xor(ps, 4);
      ps += __shfl_xor(ps, 8);
      lrun[r] = lrun[r] * alpha[r] + ps;
    }
    // ---- P split-2 -> per-wave LDS (transpose to A-frag layout) ----
#pragma unroll
    for (int ni = 0; ni < 4; ++ni)
#pragma unroll
      for (int r = 0; r < 4; ++r) {
        const float pv = accS[ni][r];
        unsigned short p1, p2;
        split2(pv, p1, p2);
        Ps1[w][lg * 4 + r][ni * 16 + lr] = p1;
        Ps2[w][lg * 4 + r][ni * 16 + lr] = p2;
      }
#pragma unroll
    for (int ni = 0; ni < 4; ++ni)
#pragma unroll
      for (int r = 0; r < 4; ++r) accO[ni][r] *= alpha[r];

    asm volatile("s_waitcnt lgkmcnt(0)" ::: "memory");

    // ---- O += P @ V ----
#pragma unroll
    for (int kk = 0; kk < 2; ++kk) {
      const int koff = kk * 32 + lg * 8;
      const bfrag pa1 = *reinterpret_cast<const bfrag*>(&Ps1[w][lr][koff]);
      const bfrag pa2 = *reinterpret_cast<const bfrag*>(&Ps2[w][lr][koff]);
#pragma unroll
      for (int ni = 0; ni < 4; ++ni) {
        const bfrag vb1 = *reinterpret_cast<const bfrag*>(&Vt1[ni * 16 + lr][koff]);
        const bfrag vb2 = *reinterpret_cast<const bfrag*>(&Vt2[ni * 16 + lr][koff]);
        f32x4 c = accO[ni];
        c = __builtin_amdgcn_mfma_f32_16x16x32_bf16(pa1, vb2, c, 0, 0, 0);
        c = __builtin_amdgcn_mfma_f32_16x16x32_bf16(pa2, vb1, c, 0, 0, 0);
        c = __builtin_amdgcn_mfma_f32_16x16x32_bf16(pa1, vb1, c, 0, 0, 0);
        accO[ni] = c;
      }
    }
    __syncthreads();
  }

  // ---- epilogue ----
  const int tqo = qt * 64 + w * 16 + lg * 4;
#pragma unroll
  for (int r = 0; r < 4; ++r) {
    const float inv = 1.0f / lrun[r];
#pragma unroll
    for (int ni = 0; ni < 4; ++ni)
      o[((size_t)(tqo + r) * 16 + h) * 64 + ni * 16 + lr] = accO[ni][r] * inv;
  }
}

// ---------- router: top-2 of softmax(h2 @ Wr) ----------
__global__ __launch_bounds__(64) void router_kernel(const float* __restrict__ h2,
                                                    const float* __restrict__ Wr,
                                                    int* __restrict__ eidx,
                                                    float* __restrict__ egate) {
  const int t = blockIdx.x;
  const int l = threadIdx.x;
  float p[8];
#pragma unroll
  for (int e = 0; e < 8; ++e) p[e] = 0.f;
  for (int d = l; d < 1024; d += 64) {
    const float x = h2[(size_t)t * 1024 + d];
    const float4 w0 = *reinterpret_cast<const float4*>(&Wr[d * 8]);
    const float4 w1 = *reinterpret_cast<const float4*>(&Wr[d * 8 + 4]);
    p[0] += x * w0.x; p[1] += x * w0.y; p[2] += x * w0.z; p[3] += x * w0.w;
    p[4] += x * w1.x; p[5] += x * w1.y; p[6] += x * w1.z; p[7] += x * w1.w;
  }
#pragma unroll
  for (int off = 32; off; off >>= 1) {
#pragma unroll
    for (int e = 0; e < 8; ++e) p[e] += __shfl_xor(p[e], off);
  }
  if (l == 0) {
    int i0 = 0; float b0 = p[0];
#pragma unroll
    for (int e = 1; e < 8; ++e) if (p[e] > b0) { b0 = p[e]; i0 = e; }
    int i1 = -1; float b1 = -INFINITY;
#pragma unroll
    for (int e = 0; e < 8; ++e) if (e != i0 && p[e] > b1) { b1 = p[e]; i1 = e; }
    const float ex = expf(b1 - b0);
    eidx[t * 2] = i0; eidx[t * 2 + 1] = i1;
    egate[t * 2] = 1.0f / (1.0f + ex);
    egate[t * 2 + 1] = ex / (1.0f + ex);
  }
}

// ---------- dispatch: replicate jnp cumsum slot assignment ----------
__global__ __launch_bounds__(256) void dispatch_kernel(
    const int* __restrict__ eidx, int* __restrict__ cnt,
    int* __restrict__ slot_token, int* __restrict__ entry_slot) {
  __shared__ unsigned char ef[2048];
  __shared__ unsigned short ch[256][8];
  const int tid = threadIdx.x;
  for (int i = tid; i < 2048; i += 256) ef[i] = (unsigned char)eidx[i];
  __syncthreads();
  int loc[8];
#pragma unroll
  for (int e = 0; e < 8; ++e) loc[e] = 0;
  const int base = tid * 8;
  for (int j = 0; j < 8; ++j) {
    const int ee = ef[base + j];
#pragma unroll
    for (int e = 0; e < 8; ++e) loc[e] += (ee == e);
  }
#pragma unroll
  for (int e = 0; e < 8; ++e) ch[tid][e] = (unsigned short)loc[e];
  __syncthreads();
  int pre[8];
#pragma unroll
  for (int e = 0; e < 8; ++e) pre[e] = 0;
  for (int t2 = 0; t2 < tid; ++t2) {
#pragma unroll
    for (int e = 0; e < 8; ++e) pre[e] += ch[t2][e];
  }
  if (tid == 255) {
#pragma unroll
    for (int e = 0; e < 8; ++e) cnt[e] = min(pre[e] + loc[e], 512);
  }
  for (int j = 0; j < 8; ++j) {
    const int i = base + j;
    const int ee = ef[i];
    int slot = 0;
#pragma unroll
    for (int e = 0; e < 8; ++e) {
      if (e == ee) { slot = pre[e]; pre[e] = pre[e] + 1; }
    }
    if (slot < 512) {
      slot_token[ee * 512 + slot] = i >> 1;
      entry_slot[i] = slot;
    } else {
      entry_slot[i] = -1;
    }
  }
}

// ---------- MoE pass 1: act = silu(X@Wg) * (X@Wu), bf16 out ----------
__global__ __launch_bounds__(256) void moe_mlp1_kernel(
    const float* __restrict__ h2, const float* __restrict__ Wg,
    const float* __restrict__ Wu, const int* __restrict__ cnt,
    const int* __restrict__ slot_token, unsigned short* __restrict__ act) {
  const int mt = blockIdx.x, nt = blockIdx.y, e = blockIdx.z;
  const int ce = cnt[e];
  if (mt * 64 >= ce) return;
  __shared__ alignas(16) unsigned short As[64][40], Bg[64][40], Bu[64][40];
  const int tid = threadIdx.x;
  const int w = tid >> 6, l = tid & 63;
  const int wm = (w >> 1) * 32, wn = (w & 1) * 32;
  const int lr = l & 15, lg = l >> 4;
  const int tkA = tid & 7, tmA = tid >> 3;
  const int tnB = tid & 63, kbB = tid >> 6;
  const int n0 = nt * 64;
  int tok[2];
#pragma unroll
  for (int p = 0; p < 2; ++p) {
    const int m = mt * 64 + tmA + p * 32;
    tok[p] = (m < ce) ? slot_token[e * 512 + m] : -1;
  }
  const float* WgE = Wg + (size_t)e * 1024 * 2048;
  const float* WuE = Wu + (size_t)e * 1024 * 2048;
  f32x4 accG[2][2] = {{{0.f,0.f,0.f,0.f},{0.f,0.f,0.f,0.f}},
                      {{0.f,0.f,0.f,0.f},{0.f,0.f,0.f,0.f}}};
  f32x4 accU[2][2] = {{{0.f,0.f,0.f,0.f},{0.f,0.f,0.f,0.f}},
                      {{0.f,0.f,0.f,0.f},{0.f,0.f,0.f,0.f}}};
  for (int k0 = 0; k0 < 1024; k0 += 32) {
#pragma unroll
    for (int p = 0; p < 2; ++p) {
      float4 va = make_float4(0.f, 0.f, 0.f, 0.f);
      if (tok[p] >= 0)
        va = *reinterpret_cast<const float4*>(&h2[(size_t)tok[p] * 1024 + k0 + tkA * 4]);
      *reinterpret_cast<ushort4*>(&As[tmA + p * 32][tkA * 4]) =
          make_ushort4(bf16_rne(va.x), bf16_rne(va.y), bf16_rne(va.z), bf16_rne(va.w));
    }
    {
      unsigned short gb[8], ub[8];
#pragma unroll
      for (int j = 0; j < 8; ++j) {
        const size_t off = (size_t)(k0 + kbB * 8 + j) * 2048 + n0 + tnB;
        gb[j] = bf16_rne(WgE[off]);
        ub[j] = bf16_rne(WuE[off]);
      }
      *reinterpret_cast<ushort4*>(&Bg[tnB][kbB * 8])     = make_ushort4(gb[0], gb[1], gb[2], gb[3]);
      *reinterpret_cast<ushort4*>(&Bg[tnB][kbB * 8 + 4]) = make_ushort4(gb[4], gb[5], gb[6], gb[7]);
      *reinterpret_cast<ushort4*>(&Bu[tnB][kbB * 8])     = make_ushort4(ub[0], ub[1], ub[2], ub[3]);
      *reinterpret_cast<ushort4*>(&Bu[tnB][kbB * 8 + 4]) = make_ushort4(ub[4], ub[5], ub[6], ub[7]);
    }
    __syncthreads();
    bfrag av[2], gv[2], uv[2];
#pragma unroll
    for (int mi = 0; mi < 2; ++mi)
      av[mi] = *reinterpret_cast<const bfrag*>(&As[wm + mi * 16 + lr][lg * 8]);
#pragma unroll
    for (int ni = 0; ni < 2; ++ni) {
      gv[ni] = *reinterpret_cast<const bfrag*>(&Bg[wn + ni * 16 + lr][lg * 8]);
      uv[ni] = *reinterpret_cast<const bfrag*>(&Bu[wn + ni * 16 + lr][lg * 8]);
    }
#pragma unroll
    for (int mi = 0; mi < 2; ++mi)
#pragma unroll
      for (int ni = 0; ni < 2; ++ni) {
        accG[mi][ni] = __builtin_amdgcn_mfma_f32_16x16x32_bf16(av[mi], gv[ni], accG[mi][ni], 0, 0, 0);
        accU[mi][ni] = __builtin_amdgcn_mfma_f32_16x16x32_bf16(av[mi], uv[ni], accU[mi][ni], 0, 0, 0);
      }
    __syncthreads();
  }
#pragma unroll
  for (int mi = 0; mi < 2; ++mi)
#pragma unroll
    for (int ni = 0; ni < 2; ++ni)
#pragma unroll
      for (int r = 0; r < 4; ++r) {
        const int m = mt * 64 + wm + mi * 16 + lg * 4 + r;
        if (m < ce) {
          const int col = n0 + wn + ni * 16 + lr;
          const float gg = accG[mi][ni][r];
          const float uu = accU[mi][ni][r];
          const float a = gg / (1.0f + expf(-gg)) * uu;
          act[((size_t)e * 512 + m) * 2048 + col] = bf16_rne(a);
        }
      }
}

// ---------- MoE pass 2: ob = act @ Wd ----------
__global__ __launch_bounds__(256) void moe_mlp2_kernel(
    const unsigned short* __restrict__ act, const float* __restrict__ Wd,
    const int* __restrict__ cnt, float* __restrict__ ob) {
  const int mt = blockIdx.x, nt = blockIdx.y, e = blockIdx.z;
  const int ce = cnt[e];
  if (mt * 64 >= ce) return;
  __shared__ alignas(16) unsigned short As[64][40], Bs[64][40];
  const int tid = threadIdx.x;
  const int w = tid >> 6, l = tid & 63;
  const int wm = (w >> 1) * 32, wn = (w & 1) * 32;
  const int lr = l & 15, lg = l >> 4;
  const int tk4 = tid & 3, tmA = tid >> 2;
  const int tnB = tid & 63, kbB = tid >> 6;
  const int n0 = nt * 64;
  const unsigned short* actE = act + (size_t)e * 512 * 2048;
  const float* WdE = Wd + (size_t)e * 2048 * 1024;
  const int mrow = mt * 64 + tmA;
  f32x4 acc[2][2] = {{{0.f,0.f,0.f,0.f},{0.f,0.f,0.f,0.f}},
                     {{0.f,0.f,0.f,0.f},{0.f,0.f,0.f,0.f}}};
  for (int k0 = 0; k0 < 2048; k0 += 32) {
    {
      float4 raw = make_float4(0.f, 0.f, 0.f, 0.f);
      if (mrow < ce)
        raw = *reinterpret_cast<const float4*>(&actE[(size_t)mrow * 2048 + k0 + tk4 * 8]);
      *reinterpret_cast<float4*>(&As[tmA][tk4 * 8]) = raw;
    }
    {
      unsigned short bb[8];
#pragma unroll
      for (int j = 0; j < 8; ++j)
        bb[j] = bf16_rne(WdE[(size_t)(k0 + kbB * 8 + j) * 1024 + n0 + tnB]);
      *reinterpret_cast<ushort4*>(&Bs[tnB][kbB * 8])     = make_ushort4(bb[0], bb[1], bb[2], bb[3]);
      *reinterpret_cast<ushort4*>(&Bs[tnB][kbB * 8 + 4]) = make_ushort4(bb[4], bb[5], bb[6], bb[7]);
    }
    __syncthreads();
    bfrag av[2], bv[2];
#pragma unroll
    for (int mi = 0; mi < 2; ++mi)
      av[mi] = *reinterpret_cast<const bfrag*>(&As[wm + mi * 16 + lr][lg * 8]);
#pragma unroll
    for (int ni = 0; ni < 2; ++ni)
      bv[ni] = *reinterpret_cast<const bfrag*>(&Bs[wn + ni * 16 + lr][lg * 8]);
#pragma unroll
    for (int mi = 0; mi < 2; ++mi)
#pragma unroll
      for (int ni = 0; ni < 2; ++ni)
        acc[mi][ni] = __builtin_amdgcn_mfma_f32_16x16x32_bf16(av[mi], bv[ni], acc[mi][ni], 0, 0, 0);
    __syncthreads();
  }
#pragma unroll
  for (int mi = 0; mi < 2; ++mi)
#pragma unroll
    for (int ni = 0; ni < 2; ++ni)
#pragma unroll
      for (int r = 0; r < 4; ++r) {
        const int m = mt * 64 + wm + mi * 16 + lg * 4 + r;
        if (m < ce) {
          const int col = n0 + wn + ni * 16 + lr;
          ob[((size_t)e * 512 + m) * 1024 + col] = acc[mi][ni][r];
        }
      }
}

// ---------- combine: out += sum_k gate * ob[e_k][slot_k] ----------
__global__ __launch_bounds__(256) void combine_kernel(
    const float* __restrict__ ob, const int* __restrict__ eidx,
    const float* __restrict__ egate, const int* __restrict__ entry_slot,
    float* __restrict__ out) {
  const int t = blockIdx.x;
  const int d = threadIdx.x * 4;
  float4 o4 = *reinterpret_cast<float4*>(&out[(size_t)t * 1024 + d]);
#pragma unroll
  for (int kk = 0; kk < 2; ++kk) {
    const int i = t * 2 + kk;
    const int s = entry_slot[i];
    if (s >= 0) {
      const int e = eidx[i];
      const float g = egate[i];
      const float4 c = *reinterpret_cast<const float4*>(&ob[((size_t)e * 512 + s) * 1024 + d]);
      o4.x += g * c.x; o4.y += g * c.y; o4.z += g * c.z; o4.w += g * c.w;
    }
  }
  *reinterpret_cast<float4*>(&out[(size_t)t * 1024 + d]) = o4;
}

extern "C" void kernel_launch(void* const* d_in, const int* in_sizes, int n_in,
                              void* d_out, int out_size, void* d_ws, size_t ws_size,
                              hipStream_t stream) {
  const float* hidden = (const float*)d_in[0];
  const int* posids  = (const int*)d_in[1];
  const float* ln1w  = (const float*)d_in[2];
  const float* ln2w  = (const float*)d_in[3];
  const float* Wq    = (const float*)d_in[4];
  const float* Wk    = (const float*)d_in[5];
  const float* Wv    = (const float*)d_in[6];
  const float* Wo    = (const float*)d_in[7];
  const float* Wr    = (const float*)d_in[8];
  const float* Wg    = (const float*)d_in[9];
  const float* Wu    = (const float*)d_in[10];
  const float* Wd    = (const float*)d_in[11];
  float* out = (float*)d_out;

  char* p = (char*)d_ws;
  auto alloc = [&](size_t bytes) { char* r = p; p += (bytes + 255) & ~(size_t)255; return r; };
  float* h1   = (float*)alloc((size_t)1024 * 1024 * 4);
  float* qb   = (float*)alloc((size_t)1024 * 1024 * 4);
  float* kb   = (float*)alloc((size_t)1024 * 256 * 4);
  float* vb   = (float*)alloc((size_t)1024 * 256 * 4);
  float* ao   = (float*)alloc((size_t)1024 * 1024 * 4);
  float* h2   = (float*)alloc((size_t)1024 * 1024 * 4);
  unsigned short* act = (unsigned short*)alloc((size_t)8 * 512 * 2048 * 2);
  float* obuf = (float*)alloc((size_t)8 * 512 * 1024 * 4);
  int* eidx   = (int*)alloc(2048 * 4);
  float* egate = (float*)alloc(2048 * 4);
  int* cnt    = (int*)alloc(8 * 4);
  int* slot_token = (int*)alloc((size_t)8 * 512 * 4);
  int* entry_slot = (int*)alloc(2048 * 4);
  float* cosT = (float*)alloc((size_t)1024 * 32 * 4);
  float* sinT = (float*)alloc((size_t)1024 * 32 * 4);
  unsigned short* Kp1 = (unsigned short*)alloc((size_t)4 * 1024 * 64 * 2);
  unsigned short* Kp2 = (unsigned short*)alloc((size_t)4 * 1024 * 64 * 2);
  unsigned short* Vp1 = (unsigned short*)alloc((size_t)4 * 1024 * 64 * 2);
  unsigned short* Vp2 = (unsigned short*)alloc((size_t)4 * 1024 * 64 * 2);

  rope_table_kernel<<<128, 256, 0, stream>>>(posids, cosT, sinT);
  ln_kernel<<<1024, 256, 0, stream>>>(hidden, ln1w, h1);
  gemm_split3_kernel<<<dim3(16, 16), 256, 0, stream>>>(h1, Wq, qb, nullptr, 1024, 1024, 1);
  gemm_split3_kernel<<<dim3(16, 4), 256, 0, stream>>>(h1, Wk, kb, nullptr, 256, 1024, 1);
  gemm_split3_kernel<<<dim3(16, 4), 256, 0, stream>>>(h1, Wv, vb, nullptr, 256, 1024, 1);
  rope_kernel<<<dim3(1024, 20), 32, 0, stream>>>(qb, kb, cosT, sinT);
  prep_kv_kernel<<<1024, 256, 0, stream>>>(kb, vb, Kp1, Kp2, Vp1, Vp2);
  attn_kernel<<<dim3(16, 16), 256, 0, stream>>>(qb, Kp1, Kp2, Vp1, Vp2, ao);
  gemm_split3_kernel<<<dim3(16, 16), 256, 0, stream>>>(ao, Wo, out, hidden, 1024, 1024, 0);
  ln_kernel<<<1024, 256, 0, stream>>>(out, ln2w, h2);
  router_kernel<<<1024, 64, 0, stream>>>(h2, Wr, eidx, egate);
  dispatch_kernel<<<1, 256, 0, stream>>>(eidx, cnt, slot_token, entry_slot);
  moe_mlp1_kernel<<<dim3(8, 32, 8), 256, 0, stream>>>(h2, Wg, Wu, cnt, slot_token, act);
  moe_mlp2_kernel<<<dim3(8, 16, 8), 256, 0, stream>>>(act, Wd, cnt, obuf);
  combine_kernel<<<1024, 256, 0, stream>>>(obuf, eidx, egate, entry_slot, out);
}

// Round 3
// 495.635 us; speedup vs baseline: 1.3546x; 1.0354x over previous
//
#include <hip/hip_runtime.h>
#include <math.h>

typedef __attribute__((ext_vector_type(8))) short bfrag;   // 8 x bf16 bits
typedef __attribute__((ext_vector_type(8))) unsigned short u16x8;
typedef __attribute__((ext_vector_type(4))) float f32x4;   // MFMA accumulator

// ---------- bf16 helpers ----------
__device__ __forceinline__ unsigned short bf16_rne(float f) {
  unsigned int u = __float_as_uint(f);
  u += 0x7FFFu + ((u >> 16) & 1u);
  return (unsigned short)(u >> 16);
}
__device__ __forceinline__ float bf16f(unsigned short h) {
  return __uint_as_float(((unsigned int)h) << 16);
}
__device__ __forceinline__ void split3(float x, unsigned short &o1, unsigned short &o2, unsigned short &o3) {
  o1 = bf16_rne(x);
  const float r1 = x - bf16f(o1);
  o2 = bf16_rne(r1);
  const float r2 = r1 - bf16f(o2);
  o3 = bf16_rne(r2);
}
__device__ __forceinline__ void split2(float x, unsigned short &o1, unsigned short &o2) {
  o1 = bf16_rne(x);
  o2 = bf16_rne(x - bf16f(o1));
}

// ---------- LayerNorm (row = 1024 f32) ----------
__global__ __launch_bounds__(256) void ln_kernel(const float* __restrict__ x,
                                                 const float* __restrict__ w,
                                                 float* __restrict__ out) {
  const int t = blockIdx.x;
  const int tid = threadIdx.x;
  const float4 v = *reinterpret_cast<const float4*>(&x[(size_t)t * 1024 + tid * 4]);
  float s = v.x + v.y + v.z + v.w;
  float ss = v.x * v.x + v.y * v.y + v.z * v.z + v.w * v.w;
#pragma unroll
  for (int off = 32; off; off >>= 1) {
    s += __shfl_xor(s, off);
    ss += __shfl_xor(ss, off);
  }
  __shared__ float red1[4], red2[4];
  if ((tid & 63) == 0) { red1[tid >> 6] = s; red2[tid >> 6] = ss; }
  __syncthreads();
  s = red1[0] + red1[1] + red1[2] + red1[3];
  ss = red2[0] + red2[1] + red2[2] + red2[3];
  const float mu = s * (1.0f / 1024.0f);
  const float var = ss * (1.0f / 1024.0f) - mu * mu;
  const float rstd = 1.0f / sqrtf(var + 1e-5f);
  const float4 wv = *reinterpret_cast<const float4*>(&w[tid * 4]);
  float4 o;
  o.x = (v.x - mu) * rstd * wv.x;
  o.y = (v.y - mu) * rstd * wv.y;
  o.z = (v.z - mu) * rstd * wv.z;
  o.w = (v.w - mu) * rstd * wv.w;
  *reinterpret_cast<float4*>(&out[(size_t)t * 1024 + tid * 4]) = o;
}

// ---------- high-precision GEMM: C = [clip]( A(MxK) @ B(KxN) ) [+ Res]
__global__ __launch_bounds__(256) void gemm_split3_kernel(
    const float* __restrict__ A, const float* __restrict__ B,
    float* __restrict__ C, const float* __restrict__ Res,
    int N, int K, int doclip) {
  __shared__ alignas(16) unsigned short A1[64][40], A2[64][40], A3[64][40];
  __shared__ alignas(16) unsigned short B1[64][40], B2[64][40], B3[64][40];
  const int tid = threadIdx.x;
  const int m0 = blockIdx.x * 64;
  const int n0 = blockIdx.y * 64;
  const int w = tid >> 6, l = tid & 63;
  const int wm = (w >> 1) * 32, wn = (w & 1) * 32;
  const int lr = l & 15, lg = l >> 4;
  const int tkA = tid & 7, tmA = tid >> 3;
  const int tnB = tid & 63, kbB = tid >> 6;

  f32x4 acc[2][2] = {{{0.f,0.f,0.f,0.f},{0.f,0.f,0.f,0.f}},
                     {{0.f,0.f,0.f,0.f},{0.f,0.f,0.f,0.f}}};

  for (int k0 = 0; k0 < K; k0 += 32) {
#pragma unroll
    for (int p = 0; p < 2; ++p) {
      const int m = tmA + p * 32;
      const float4 va = *reinterpret_cast<const float4*>(&A[(size_t)(m0 + m) * K + k0 + tkA * 4]);
      unsigned short h1[4], h2[4], h3[4];
      split3(va.x, h1[0], h2[0], h3[0]);
      split3(va.y, h1[1], h2[1], h3[1]);
      split3(va.z, h1[2], h2[2], h3[2]);
      split3(va.w, h1[3], h2[3], h3[3]);
      *reinterpret_cast<ushort4*>(&A1[m][tkA * 4]) = make_ushort4(h1[0], h1[1], h1[2], h1[3]);
      *reinterpret_cast<ushort4*>(&A2[m][tkA * 4]) = make_ushort4(h2[0], h2[1], h2[2], h2[3]);
      *reinterpret_cast<ushort4*>(&A3[m][tkA * 4]) = make_ushort4(h3[0], h3[1], h3[2], h3[3]);
    }
    {
      unsigned short b1[8], b2[8], b3[8];
#pragma unroll
      for (int j = 0; j < 8; ++j) {
        const float vb = B[(size_t)(k0 + kbB * 8 + j) * N + n0 + tnB];
        split3(vb, b1[j], b2[j], b3[j]);
      }
      *reinterpret_cast<ushort4*>(&B1[tnB][kbB * 8])     = make_ushort4(b1[0], b1[1], b1[2], b1[3]);
      *reinterpret_cast<ushort4*>(&B1[tnB][kbB * 8 + 4]) = make_ushort4(b1[4], b1[5], b1[6], b1[7]);
      *reinterpret_cast<ushort4*>(&B2[tnB][kbB * 8])     = make_ushort4(b2[0], b2[1], b2[2], b2[3]);
      *reinterpret_cast<ushort4*>(&B2[tnB][kbB * 8 + 4]) = make_ushort4(b2[4], b2[5], b2[6], b2[7]);
      *reinterpret_cast<ushort4*>(&B3[tnB][kbB * 8])     = make_ushort4(b3[0], b3[1], b3[2], b3[3]);
      *reinterpret_cast<ushort4*>(&B3[tnB][kbB * 8 + 4]) = make_ushort4(b3[4], b3[5], b3[6], b3[7]);
    }
    __syncthreads();
    bfrag af[2][3], bg[2][3];
#pragma unroll
    for (int mi = 0; mi < 2; ++mi) {
      const int ar = wm + mi * 16 + lr;
      af[mi][0] = *reinterpret_cast<const bfrag*>(&A1[ar][lg * 8]);
      af[mi][1] = *reinterpret_cast<const bfrag*>(&A2[ar][lg * 8]);
      af[mi][2] = *reinterpret_cast<const bfrag*>(&A3[ar][lg * 8]);
    }
#pragma unroll
    for (int ni = 0; ni < 2; ++ni) {
      const int br = wn + ni * 16 + lr;
      bg[ni][0] = *reinterpret_cast<const bfrag*>(&B1[br][lg * 8]);
      bg[ni][1] = *reinterpret_cast<const bfrag*>(&B2[br][lg * 8]);
      bg[ni][2] = *reinterpret_cast<const bfrag*>(&B3[br][lg * 8]);
    }
#pragma unroll
    for (int mi = 0; mi < 2; ++mi)
#pragma unroll
      for (int ni = 0; ni < 2; ++ni) {
        f32x4 c = acc[mi][ni];
        c = __builtin_amdgcn_mfma_f32_16x16x32_bf16(af[mi][2], bg[ni][0], c, 0, 0, 0);
        c = __builtin_amdgcn_mfma_f32_16x16x32_bf16(af[mi][1], bg[ni][1], c, 0, 0, 0);
        c = __builtin_amdgcn_mfma_f32_16x16x32_bf16(af[mi][0], bg[ni][2], c, 0, 0, 0);
        c = __builtin_amdgcn_mfma_f32_16x16x32_bf16(af[mi][1], bg[ni][0], c, 0, 0, 0);
        c = __builtin_amdgcn_mfma_f32_16x16x32_bf16(af[mi][0], bg[ni][1], c, 0, 0, 0);
        c = __builtin_amdgcn_mfma_f32_16x16x32_bf16(af[mi][0], bg[ni][0], c, 0, 0, 0);
        acc[mi][ni] = c;
      }
    __syncthreads();
  }
#pragma unroll
  for (int mi = 0; mi < 2; ++mi)
#pragma unroll
    for (int ni = 0; ni < 2; ++ni)
#pragma unroll
      for (int r = 0; r < 4; ++r) {
        const int row = m0 + wm + mi * 16 + lg * 4 + r;
        const int col = n0 + wn + ni * 16 + lr;
        float vv = acc[mi][ni][r];
        if (doclip) vv = fminf(fmaxf(vv, -8.0f), 8.0f);
        if (Res) vv += Res[(size_t)row * N + col];
        C[(size_t)row * N + col] = vv;
      }
}

// ---------- RoPE table (f64 trig, computed once) ----------
__global__ void rope_table_kernel(const int* __restrict__ posids,
                                  float* __restrict__ cosT, float* __restrict__ sinT) {
  const int t = blockIdx.x * 8 + (threadIdx.x >> 5);
  const int i = threadIdx.x & 31;
  const double ang = (double)posids[t] * pow(500000.0, -(double)i / 32.0);
  cosT[t * 32 + i] = (float)cos(ang);
  sinT[t * 32 + i] = (float)sin(ang);
}

// ---------- RoPE apply on q (T,16,64) and k (T,4,64) ----------
__global__ void rope_kernel(float* __restrict__ q, float* __restrict__ k,
                            const float* __restrict__ cosT, const float* __restrict__ sinT) {
  const int t = blockIdx.x;
  const int hh = blockIdx.y;   // 0..19: 16 q heads then 4 k heads
  const int i = threadIdx.x;   // 0..31
  float* ptr = (hh < 16) ? &q[((size_t)t * 16 + hh) * 64]
                         : &k[((size_t)t * 4 + (hh - 16)) * 64];
  const float c = cosT[t * 32 + i], s = sinT[t * 32 + i];
  const float u1 = ptr[i], u2 = ptr[i + 32];
  ptr[i]      = u1 * c - u2 * s;
  ptr[i + 32] = u2 * c + u1 * s;
}

// ---------- prep: split-2 bf16 K (row-major) and V (transposed) ----------
__global__ __launch_bounds__(256) void prep_kv_kernel(
    const float* __restrict__ k, const float* __restrict__ v,
    unsigned short* __restrict__ Kp1, unsigned short* __restrict__ Kp2,
    unsigned short* __restrict__ Vp1, unsigned short* __restrict__ Vp2) {
  const int key = blockIdx.x;          // 0..1023
  const int kvh = threadIdx.x >> 6;    // 0..3
  const int d = threadIdx.x & 63;
  const float kk = k[((size_t)key * 4 + kvh) * 64 + d];
  const float vv = v[((size_t)key * 4 + kvh) * 64 + d];
  unsigned short a1, a2, b1, b2;
  split2(kk, a1, a2);
  split2(vv, b1, b2);
  const size_t ki = ((size_t)kvh * 1024 + key) * 64 + d;
  Kp1[ki] = a1; Kp2[ki] = a2;
  const size_t vi = ((size_t)kvh * 64 + d) * 1024 + key;
  Vp1[vi] = b1; Vp2[vi] = b2;
}

// ---------- causal GQA flash attention, split-2 bf16 MFMA ----------
__global__ __launch_bounds__(256) void attn_kernel(
    const float* __restrict__ q,
    const unsigned short* __restrict__ Kp1, const unsigned short* __restrict__ Kp2,
    const unsigned short* __restrict__ Vp1, const unsigned short* __restrict__ Vp2,
    float* __restrict__ o) {
  const int qt = blockIdx.x, h = blockIdx.y, kvh = h >> 2;
  __shared__ unsigned short Ks1[64][72], Ks2[64][72], Vt1[64][72], Vt2[64][72];
  __shared__ unsigned short Ps1[4][16][72], Ps2[4][16][72];
  const int tid = threadIdx.x;
  const int w = tid >> 6, l = tid & 63;
  const int lr = l & 15, lg = l >> 4;

  bfrag aq1[2], aq2[2];
  {
    const int tq = qt * 64 + w * 16 + lr;
    const float* qrow = &q[((size_t)tq * 16 + h) * 64];
#pragma unroll
    for (int ks = 0; ks < 2; ++ks) {
      const int d0 = ks * 32 + lg * 8;
      const float4 f0 = *reinterpret_cast<const float4*>(qrow + d0);
      const float4 f1 = *reinterpret_cast<const float4*>(qrow + d0 + 4);
      const float xv[8] = {f0.x, f0.y, f0.z, f0.w, f1.x, f1.y, f1.z, f1.w};
#pragma unroll
      for (int j = 0; j < 8; ++j) {
        const float xs = xv[j] * 0.125f;
        unsigned short p1, p2;
        split2(xs, p1, p2);
        aq1[ks][j] = (short)p1;
        aq2[ks][j] = (short)p2;
      }
    }
  }

  f32x4 accO[4] = {{0.f,0.f,0.f,0.f},{0.f,0.f,0.f,0.f},{0.f,0.f,0.f,0.f},{0.f,0.f,0.f,0.f}};
  float mrun[4] = {-INFINITY, -INFINITY, -INFINITY, -INFINITY};
  float lrun[4] = {0.f, 0.f, 0.f, 0.f};

  for (int ti = 0; ti <= qt; ++ti) {
    const int s0 = ti * 64;
    {
      const size_t kbase = ((size_t)kvh * 1024 + s0 + l) * 64 + w * 16;
      *reinterpret_cast<u16x8*>(&Ks1[l][w * 16])     = *reinterpret_cast<const u16x8*>(&Kp1[kbase]);
      *reinterpret_cast<u16x8*>(&Ks1[l][w * 16 + 8]) = *reinterpret_cast<const u16x8*>(&Kp1[kbase + 8]);
      *reinterpret_cast<u16x8*>(&Ks2[l][w * 16])     = *reinterpret_cast<const u16x8*>(&Kp2[kbase]);
      *reinterpret_cast<u16x8*>(&Ks2[l][w * 16 + 8]) = *reinterpret_cast<const u16x8*>(&Kp2[kbase + 8]);
      const size_t vbase = ((size_t)kvh * 64 + l) * 1024 + s0 + w * 16;
      *reinterpret_cast<u16x8*>(&Vt1[l][w * 16])     = *reinterpret_cast<const u16x8*>(&Vp1[vbase]);
      *reinterpret_cast<u16x8*>(&Vt1[l][w * 16 + 8]) = *reinterpret_cast<const u16x8*>(&Vp1[vbase + 8]);
      *reinterpret_cast<u16x8*>(&Vt2[l][w * 16])     = *reinterpret_cast<const u16x8*>(&Vp2[vbase]);
      *reinterpret_cast<u16x8*>(&Vt2[l][w * 16 + 8]) = *reinterpret_cast<const u16x8*>(&Vp2[vbase + 8]);
    }
    __syncthreads();

    f32x4 accS[4] = {{0.f,0.f,0.f,0.f},{0.f,0.f,0.f,0.f},{0.f,0.f,0.f,0.f},{0.f,0.f,0.f,0.f}};
#pragma unroll
    for (int ks = 0; ks < 2; ++ks) {
      const int koff = ks * 32 + lg * 8;
#pragma unroll
      for (int ni = 0; ni < 4; ++ni) {
        const bfrag b1 = *reinterpret_cast<const bfrag*>(&Ks1[ni * 16 + lr][koff]);
        const bfrag b2 = *reinterpret_cast<const bfrag*>(&Ks2[ni * 16 + lr][koff]);
        f32x4 c = accS[ni];
        c = __builtin_amdgcn_mfma_f32_16x16x32_bf16(aq1[ks], b2, c, 0, 0, 0);
        c = __builtin_amdgcn_mfma_f32_16x16x32_bf16(aq2[ks], b1, c, 0, 0, 0);
        c = __builtin_amdgcn_mfma_f32_16x16x32_bf16(aq1[ks], b1, c, 0, 0, 0);
        accS[ni] = c;
      }
    }
    if (ti == qt) {
      const int rowb = w * 16 + lg * 4;
#pragma unroll
      for (int ni = 0; ni < 4; ++ni)
#pragma unroll
        for (int r = 0; r < 4; ++r)
          if (ni * 16 + lr > rowb + r) accS[ni][r] = -INFINITY;
    }
    float alpha[4];
#pragma unroll
    for (int r = 0; r < 4; ++r) {
      float tm = fmaxf(fmaxf(accS[0][r], accS[1][r]), fmaxf(accS[2][r], accS[3][r]));
      tm = fmaxf(tm, __shfl_xor(tm, 1));
      tm = fmaxf(tm, __shfl_xor(tm, 2));
      tm = fmaxf(tm, __shfl_xor(tm, 4));
      tm = fmaxf(tm, __shfl_xor(tm, 8));
      const float mnew = fmaxf(mrun[r], tm);
      alpha[r] = __expf(mrun[r] - mnew);
      mrun[r] = mnew;
      float ps = 0.f;
#pragma unroll
      for (int ni = 0; ni < 4; ++ni) {
        const float pv = __expf(accS[ni][r] - mnew);
        accS[ni][r] = pv;
        ps += pv;
      }
      ps += __shfl_xor(ps, 1);
      ps += __shfl_xor(ps, 2);
      ps += __shfl_xor(ps, 4);
      ps += __shfl_xor(ps, 8);
      lrun[r] = lrun[r] * alpha[r] + ps;
    }
#pragma unroll
    for (int ni = 0; ni < 4; ++ni)
#pragma unroll
      for (int r = 0; r < 4; ++r) {
        const float pv = accS[ni][r];
        unsigned short p1, p2;
        split2(pv, p1, p2);
        Ps1[w][lg * 4 + r][ni * 16 + lr] = p1;
        Ps2[w][lg * 4 + r][ni * 16 + lr] = p2;
      }
#pragma unroll
    for (int ni = 0; ni < 4; ++ni)
#pragma unroll
      for (int r = 0; r < 4; ++r) accO[ni][r] *= alpha[r];

    asm volatile("s_waitcnt lgkmcnt(0)" ::: "memory");

#pragma unroll
    for (int kk = 0; kk < 2; ++kk) {
      const int koff = kk * 32 + lg * 8;
      const bfrag pa1 = *reinterpret_cast<const bfrag*>(&Ps1[w][lr][koff]);
      const bfrag pa2 = *reinterpret_cast<const bfrag*>(&Ps2[w][lr][koff]);
#pragma unroll
      for (int ni = 0; ni < 4; ++ni) {
        const bfrag vb1 = *reinterpret_cast<const bfrag*>(&Vt1[ni * 16 + lr][koff]);
        const bfrag vb2 = *reinterpret_cast<const bfrag*>(&Vt2[ni * 16 + lr][koff]);
        f32x4 c = accO[ni];
        c = __builtin_amdgcn_mfma_f32_16x16x32_bf16(pa1, vb2, c, 0, 0, 0);
        c = __builtin_amdgcn_mfma_f32_16x16x32_bf16(pa2, vb1, c, 0, 0, 0);
        c = __builtin_amdgcn_mfma_f32_16x16x32_bf16(pa1, vb1, c, 0, 0, 0);
        accO[ni] = c;
      }
    }
    __syncthreads();
  }

  const int tqo = qt * 64 + w * 16 + lg * 4;
#pragma unroll
  for (int r = 0; r < 4; ++r) {
    const float inv = 1.0f / lrun[r];
#pragma unroll
    for (int ni = 0; ni < 4; ++ni)
      o[((size_t)(tqo + r) * 16 + h) * 64 + ni * 16 + lr] = accO[ni][r] * inv;
  }
}

// ---------- router: top-2 of softmax(h2 @ Wr) ----------
__global__ __launch_bounds__(64) void router_kernel(const float* __restrict__ h2,
                                                    const float* __restrict__ Wr,
                                                    int* __restrict__ eidx,
                                                    float* __restrict__ egate) {
  const int t = blockIdx.x;
  const int l = threadIdx.x;
  float p[8];
#pragma unroll
  for (int e = 0; e < 8; ++e) p[e] = 0.f;
  for (int d = l; d < 1024; d += 64) {
    const float x = h2[(size_t)t * 1024 + d];
    const float4 w0 = *reinterpret_cast<const float4*>(&Wr[d * 8]);
    const float4 w1 = *reinterpret_cast<const float4*>(&Wr[d * 8 + 4]);
    p[0] += x * w0.x; p[1] += x * w0.y; p[2] += x * w0.z; p[3] += x * w0.w;
    p[4] += x * w1.x; p[5] += x * w1.y; p[6] += x * w1.z; p[7] += x * w1.w;
  }
#pragma unroll
  for (int off = 32; off; off >>= 1) {
#pragma unroll
    for (int e = 0; e < 8; ++e) p[e] += __shfl_xor(p[e], off);
  }
  if (l == 0) {
    int i0 = 0; float b0 = p[0];
#pragma unroll
    for (int e = 1; e < 8; ++e) if (p[e] > b0) { b0 = p[e]; i0 = e; }
    int i1 = -1; float b1 = -INFINITY;
#pragma unroll
    for (int e = 0; e < 8; ++e) if (e != i0 && p[e] > b1) { b1 = p[e]; i1 = e; }
    const float ex = expf(b1 - b0);
    eidx[t * 2] = i0; eidx[t * 2 + 1] = i1;
    egate[t * 2] = 1.0f / (1.0f + ex);
    egate[t * 2 + 1] = ex / (1.0f + ex);
  }
}

// ---------- dispatch: replicate jnp cumsum slot assignment ----------
__global__ __launch_bounds__(256) void dispatch_kernel(
    const int* __restrict__ eidx, int* __restrict__ cnt,
    int* __restrict__ slot_token, int* __restrict__ entry_slot) {
  __shared__ unsigned char ef[2048];
  __shared__ unsigned short ch[256][8];
  const int tid = threadIdx.x;
  for (int i = tid; i < 2048; i += 256) ef[i] = (unsigned char)eidx[i];
  __syncthreads();
  int loc[8];
#pragma unroll
  for (int e = 0; e < 8; ++e) loc[e] = 0;
  const int base = tid * 8;
  for (int j = 0; j < 8; ++j) {
    const int ee = ef[base + j];
#pragma unroll
    for (int e = 0; e < 8; ++e) loc[e] += (ee == e);
  }
#pragma unroll
  for (int e = 0; e < 8; ++e) ch[tid][e] = (unsigned short)loc[e];
  __syncthreads();
  int pre[8];
#pragma unroll
  for (int e = 0; e < 8; ++e) pre[e] = 0;
  for (int t2 = 0; t2 < tid; ++t2) {
#pragma unroll
    for (int e = 0; e < 8; ++e) pre[e] += ch[t2][e];
  }
  if (tid == 255) {
#pragma unroll
    for (int e = 0; e < 8; ++e) cnt[e] = min(pre[e] + loc[e], 512);
  }
  for (int j = 0; j < 8; ++j) {
    const int i = base + j;
    const int ee = ef[i];
    int slot = 0;
#pragma unroll
    for (int e = 0; e < 8; ++e) {
      if (e == ee) { slot = pre[e]; pre[e] = pre[e] + 1; }
    }
    if (slot < 512) {
      slot_token[ee * 512 + slot] = i >> 1;
      entry_slot[i] = slot;
    } else {
      entry_slot[i] = -1;
    }
  }
}

// ---------- MoE pass 1 (one-weight-pass): act = silu(X@Wg)*(X@Wu) ----------
// grid (nt=64 [BN=32], e=8); BM=256 with in-block m-chunk loop; BK=32
__global__ __launch_bounds__(256, 2) void moe_mlp1_kernel(
    const float* __restrict__ h2, const float* __restrict__ Wg,
    const float* __restrict__ Wu, const int* __restrict__ cnt,
    const int* __restrict__ slot_token, unsigned short* __restrict__ act) {
  const int nt = blockIdx.x, e = blockIdx.y;
  const int n0 = nt * 32;
  const int ce = cnt[e];
  if (ce <= 0) return;
  __shared__ alignas(16) unsigned short As[256][40];
  __shared__ alignas(16) unsigned short Bg[32][40], Bu[32][40];
  const int tid = threadIdx.x;
  const int w = tid >> 6, l = tid & 63;
  const int lr = l & 15, lg = l >> 4;
  const int wc = tid & 31, kq = tid >> 5;     // weight staging: col, k-quad
  const float* WgE = Wg + (size_t)e * 1024 * 2048 + n0;
  const float* WuE = Wu + (size_t)e * 1024 * 2048 + n0;
  const int nchunk = (ce + 255) >> 8;

  for (int mc = 0; mc < nchunk; ++mc) {
    const int slot = mc * 256 + tid;
    const int tok = (slot < ce) ? slot_token[e * 512 + slot] : -1;
    f32x4 accG[4][2], accU[4][2];
#pragma unroll
    for (int mi = 0; mi < 4; ++mi)
#pragma unroll
      for (int ni = 0; ni < 2; ++ni) {
        accG[mi][ni] = (f32x4){0.f, 0.f, 0.f, 0.f};
        accU[mi][ni] = (f32x4){0.f, 0.f, 0.f, 0.f};
      }

    for (int k0 = 0; k0 < 1024; k0 += 32) {
      // ---- stage A: thread = one token row, 32 k ----
      {
        float buf[32];
        if (tok >= 0) {
          const float* src = &h2[(size_t)tok * 1024 + k0];
#pragma unroll
          for (int j = 0; j < 8; ++j) {
            const float4 f = *reinterpret_cast<const float4*>(src + j * 4);
            buf[j * 4 + 0] = f.x; buf[j * 4 + 1] = f.y;
            buf[j * 4 + 2] = f.z; buf[j * 4 + 3] = f.w;
          }
        } else {
#pragma unroll
          for (int j = 0; j < 32; ++j) buf[j] = 0.f;
        }
#pragma unroll
        for (int j2 = 0; j2 < 4; ++j2) {
          u16x8 v8;
#pragma unroll
          for (int j = 0; j < 8; ++j) v8[j] = bf16_rne(buf[j2 * 8 + j]);
          *reinterpret_cast<u16x8*>(&As[tid][j2 * 8]) = v8;
        }
      }
      // ---- stage weights (32k x 32n each) ----
      {
        float gv[4], uv[4];
#pragma unroll
        for (int j = 0; j < 4; ++j) {
          const size_t off = (size_t)(k0 + kq * 4 + j) * 2048 + wc;
          gv[j] = WgE[off];
          uv[j] = WuE[off];
        }
        *reinterpret_cast<ushort4*>(&Bg[wc][kq * 4]) =
            make_ushort4(bf16_rne(gv[0]), bf16_rne(gv[1]), bf16_rne(gv[2]), bf16_rne(gv[3]));
        *reinterpret_cast<ushort4*>(&Bu[wc][kq * 4]) =
            make_ushort4(bf16_rne(uv[0]), bf16_rne(uv[1]), bf16_rne(uv[2]), bf16_rne(uv[3]));
      }
      __syncthreads();
      bfrag af[4], bgf[2], buf2[2];
#pragma unroll
      for (int mi = 0; mi < 4; ++mi)
        af[mi] = *reinterpret_cast<const bfrag*>(&As[w * 64 + mi * 16 + lr][lg * 8]);
#pragma unroll
      for (int ni = 0; ni < 2; ++ni) {
        bgf[ni] = *reinterpret_cast<const bfrag*>(&Bg[ni * 16 + lr][lg * 8]);
        buf2[ni] = *reinterpret_cast<const bfrag*>(&Bu[ni * 16 + lr][lg * 8]);
      }
#pragma unroll
      for (int mi = 0; mi < 4; ++mi)
#pragma unroll
        for (int ni = 0; ni < 2; ++ni) {
          accG[mi][ni] = __builtin_amdgcn_mfma_f32_16x16x32_bf16(af[mi], bgf[ni], accG[mi][ni], 0, 0, 0);
          accU[mi][ni] = __builtin_amdgcn_mfma_f32_16x16x32_bf16(af[mi], buf2[ni], accU[mi][ni], 0, 0, 0);
        }
      __syncthreads();
    }
    // ---- epilogue ----
#pragma unroll
    for (int mi = 0; mi < 4; ++mi) {
      const int mlocal = w * 64 + mi * 16 + lg * 4;
#pragma unroll
      for (int r = 0; r < 4; ++r) {
        const int m = mc * 256 + mlocal + r;
        if (m < ce) {
#pragma unroll
          for (int ni = 0; ni < 2; ++ni) {
            const int col = n0 + ni * 16 + lr;
            const float gg = accG[mi][ni][r];
            const float uu = accU[mi][ni][r];
            const float a = gg / (1.0f + __expf(-gg)) * uu;
            act[((size_t)e * 512 + m) * 2048 + col] = bf16_rne(a);
          }
        }
      }
    }
  }
}

// ---------- MoE pass 2 (one-weight-pass, split-K=2): ob_part = act @ Wd ----------
// grid (nt=32 [BN=32], e=8, kc=2); BM=256 with in-block m-chunk loop; BK=32
__global__ __launch_bounds__(256, 2) void moe_mlp2_kernel(
    const unsigned short* __restrict__ act, const float* __restrict__ Wd,
    const int* __restrict__ cnt, float* __restrict__ ob) {
  const int nt = blockIdx.x, e = blockIdx.y, kc = blockIdx.z;
  const int n0 = nt * 32;
  const int ce = cnt[e];
  if (ce <= 0) return;
  __shared__ alignas(16) unsigned short As[256][40];
  __shared__ alignas(16) unsigned short Bs[32][40];
  const int tid = threadIdx.x;
  const int w = tid >> 6, l = tid & 63;
  const int lr = l & 15, lg = l >> 4;
  const int wc = tid & 31, kq = tid >> 5;
  const unsigned short* actE = act + (size_t)e * 512 * 2048;
  const float* WdE = Wd + (size_t)e * 2048 * 1024 + n0;
  float* obE = ob + (size_t)kc * 8 * 512 * 1024;
  const int kbeg = kc * 1024, kend = kbeg + 1024;
  const int nchunk = (ce + 255) >> 8;

  for (int mc = 0; mc < nchunk; ++mc) {
    const int mrow = mc * 256 + tid;
    f32x4 acc[4][2];
#pragma unroll
    for (int mi = 0; mi < 4; ++mi)
#pragma unroll
      for (int ni = 0; ni < 2; ++ni) acc[mi][ni] = (f32x4){0.f, 0.f, 0.f, 0.f};

    for (int k0 = kbeg; k0 < kend; k0 += 32) {
      // ---- stage A (bf16 copy) ----
#pragma unroll
      for (int j2 = 0; j2 < 4; ++j2)
        *reinterpret_cast<u16x8*>(&As[tid][j2 * 8]) =
            *reinterpret_cast<const u16x8*>(&actE[(size_t)mrow * 2048 + k0 + j2 * 8]);
      // ---- stage Wd (32k x 32n) ----
      {
        float dv[4];
#pragma unroll
        for (int j = 0; j < 4; ++j)
          dv[j] = WdE[(size_t)(k0 + kq * 4 + j) * 1024 + wc];
        *reinterpret_cast<ushort4*>(&Bs[wc][kq * 4]) =
            make_ushort4(bf16_rne(dv[0]), bf16_rne(dv[1]), bf16_rne(dv[2]), bf16_rne(dv[3]));
      }
      __syncthreads();
      bfrag af[4], bf2[2];
#pragma unroll
      for (int mi = 0; mi < 4; ++mi)
        af[mi] = *reinterpret_cast<const bfrag*>(&As[w * 64 + mi * 16 + lr][lg * 8]);
#pragma unroll
      for (int ni = 0; ni < 2; ++ni)
        bf2[ni] = *reinterpret_cast<const bfrag*>(&Bs[ni * 16 + lr][lg * 8]);
#pragma unroll
      for (int mi = 0; mi < 4; ++mi)
#pragma unroll
        for (int ni = 0; ni < 2; ++ni)
          acc[mi][ni] = __builtin_amdgcn_mfma_f32_16x16x32_bf16(af[mi], bf2[ni], acc[mi][ni], 0, 0, 0);
      __syncthreads();
    }
#pragma unroll
    for (int mi = 0; mi < 4; ++mi) {
      const int mlocal = w * 64 + mi * 16 + lg * 4;
#pragma unroll
      for (int r = 0; r < 4; ++r) {
        const int m = mc * 256 + mlocal + r;
        if (m < ce) {
#pragma unroll
          for (int ni = 0; ni < 2; ++ni)
            obE[((size_t)e * 512 + m) * 1024 + n0 + ni * 16 + lr] = acc[mi][ni][r];
        }
      }
    }
  }
}

// ---------- combine: out += sum_k gate * (ob0+ob1)[e_k][slot_k] ----------
__global__ __launch_bounds__(256) void combine_kernel(
    const float* __restrict__ ob, const int* __restrict__ eidx,
    const float* __restrict__ egate, const int* __restrict__ entry_slot,
    float* __restrict__ out) {
  const int t = blockIdx.x;
  const int d = threadIdx.x * 4;
  const size_t half = (size_t)8 * 512 * 1024;
  float4 o4 = *reinterpret_cast<float4*>(&out[(size_t)t * 1024 + d]);
#pragma unroll
  for (int kk = 0; kk < 2; ++kk) {
    const int i = t * 2 + kk;
    const int s = entry_slot[i];
    if (s >= 0) {
      const int e = eidx[i];
      const float g = egate[i];
      const size_t base = ((size_t)e * 512 + s) * 1024 + d;
      const float4 c0 = *reinterpret_cast<const float4*>(&ob[base]);
      const float4 c1 = *reinterpret_cast<const float4*>(&ob[half + base]);
      o4.x += g * (c0.x + c1.x); o4.y += g * (c0.y + c1.y);
      o4.z += g * (c0.z + c1.z); o4.w += g * (c0.w + c1.w);
    }
  }
  *reinterpret_cast<float4*>(&out[(size_t)t * 1024 + d]) = o4;
}

extern "C" void kernel_launch(void* const* d_in, const int* in_sizes, int n_in,
                              void* d_out, int out_size, void* d_ws, size_t ws_size,
                              hipStream_t stream) {
  const float* hidden = (const float*)d_in[0];
  const int* posids  = (const int*)d_in[1];
  const float* ln1w  = (const float*)d_in[2];
  const float* ln2w  = (const float*)d_in[3];
  const float* Wq    = (const float*)d_in[4];
  const float* Wk    = (const float*)d_in[5];
  const float* Wv    = (const float*)d_in[6];
  const float* Wo    = (const float*)d_in[7];
  const float* Wr    = (const float*)d_in[8];
  const float* Wg    = (const float*)d_in[9];
  const float* Wu    = (const float*)d_in[10];
  const float* Wd    = (const float*)d_in[11];
  float* out = (float*)d_out;

  char* p = (char*)d_ws;
  auto alloc = [&](size_t bytes) { char* r = p; p += (bytes + 255) & ~(size_t)255; return r; };
  float* h1   = (float*)alloc((size_t)1024 * 1024 * 4);
  float* qb   = (float*)alloc((size_t)1024 * 1024 * 4);
  float* kb   = (float*)alloc((size_t)1024 * 256 * 4);
  float* vb   = (float*)alloc((size_t)1024 * 256 * 4);
  float* ao   = (float*)alloc((size_t)1024 * 1024 * 4);
  float* h2   = (float*)alloc((size_t)1024 * 1024 * 4);
  unsigned short* act = (unsigned short*)alloc((size_t)8 * 512 * 2048 * 2);
  float* obuf = (float*)alloc((size_t)2 * 8 * 512 * 1024 * 4);
  int* eidx   = (int*)alloc(2048 * 4);
  float* egate = (float*)alloc(2048 * 4);
  int* cnt    = (int*)alloc(8 * 4);
  int* slot_token = (int*)alloc((size_t)8 * 512 * 4);
  int* entry_slot = (int*)alloc(2048 * 4);
  float* cosT = (float*)alloc((size_t)1024 * 32 * 4);
  float* sinT = (float*)alloc((size_t)1024 * 32 * 4);
  unsigned short* Kp1 = (unsigned short*)alloc((size_t)4 * 1024 * 64 * 2);
  unsigned short* Kp2 = (unsigned short*)alloc((size_t)4 * 1024 * 64 * 2);
  unsigned short* Vp1 = (unsigned short*)alloc((size_t)4 * 1024 * 64 * 2);
  unsigned short* Vp2 = (unsigned short*)alloc((size_t)4 * 1024 * 64 * 2);

  rope_table_kernel<<<128, 256, 0, stream>>>(posids, cosT, sinT);
  ln_kernel<<<1024, 256, 0, stream>>>(hidden, ln1w, h1);
  gemm_split3_kernel<<<dim3(16, 16), 256, 0, stream>>>(h1, Wq, qb, nullptr, 1024, 1024, 1);
  gemm_split3_kernel<<<dim3(16, 4), 256, 0, stream>>>(h1, Wk, kb, nullptr, 256, 1024, 1);
  gemm_split3_kernel<<<dim3(16, 4), 256, 0, stream>>>(h1, Wv, vb, nullptr, 256, 1024, 1);
  rope_kernel<<<dim3(1024, 20), 32, 0, stream>>>(qb, kb, cosT, sinT);
  prep_kv_kernel<<<1024, 256, 0, stream>>>(kb, vb, Kp1, Kp2, Vp1, Vp2);
  attn_kernel<<<dim3(16, 16), 256, 0, stream>>>(qb, Kp1, Kp2, Vp1, Vp2, ao);
  gemm_split3_kernel<<<dim3(16, 16), 256, 0, stream>>>(ao, Wo, out, hidden, 1024, 1024, 0);
  ln_kernel<<<1024, 256, 0, stream>>>(out, ln2w, h2);
  router_kernel<<<1024, 64, 0, stream>>>(h2, Wr, eidx, egate);
  dispatch_kernel<<<1, 256, 0, stream>>>(eidx, cnt, slot_token, entry_slot);
  moe_mlp1_kernel<<<dim3(64, 8), 256, 0, stream>>>(h2, Wg, Wu, cnt, slot_token, act);
  moe_mlp2_kernel<<<dim3(32, 8, 2), 256, 0, stream>>>(act, Wd, cnt, obuf);
  combine_kernel<<<1024, 256, 0, stream>>>(obuf, eidx, egate, entry_slot, out);
}

// Round 4
// 442.783 us; speedup vs baseline: 1.5163x; 1.1194x over previous
//
#include <hip/hip_runtime.h>
#include <math.h>

typedef __attribute__((ext_vector_type(8))) short bfrag;   // 8 x bf16 bits
typedef __attribute__((ext_vector_type(8))) unsigned short u16x8;
typedef __attribute__((ext_vector_type(4))) float f32x4;   // MFMA accumulator

// ---------- bf16 helpers ----------
__device__ __forceinline__ unsigned short bf16_rne(float f) {
  unsigned int u = __float_as_uint(f);
  u += 0x7FFFu + ((u >> 16) & 1u);
  return (unsigned short)(u >> 16);
}
__device__ __forceinline__ float bf16f(unsigned short h) {
  return __uint_as_float(((unsigned int)h) << 16);
}
__device__ __forceinline__ void split3(float x, unsigned short &o1, unsigned short &o2, unsigned short &o3) {
  o1 = bf16_rne(x);
  const float r1 = x - bf16f(o1);
  o2 = bf16_rne(r1);
  const float r2 = r1 - bf16f(o2);
  o3 = bf16_rne(r2);
}
__device__ __forceinline__ void split2(float x, unsigned short &o1, unsigned short &o2) {
  o1 = bf16_rne(x);
  o2 = bf16_rne(x - bf16f(o1));
}

// ---------- LayerNorm (row = 1024 f32) ----------
__global__ __launch_bounds__(256) void ln_kernel(const float* __restrict__ x,
                                                 const float* __restrict__ w,
                                                 float* __restrict__ out) {
  const int t = blockIdx.x;
  const int tid = threadIdx.x;
  const float4 v = *reinterpret_cast<const float4*>(&x[(size_t)t * 1024 + tid * 4]);
  float s = v.x + v.y + v.z + v.w;
  float ss = v.x * v.x + v.y * v.y + v.z * v.z + v.w * v.w;
#pragma unroll
  for (int off = 32; off; off >>= 1) {
    s += __shfl_xor(s, off);
    ss += __shfl_xor(ss, off);
  }
  __shared__ float red1[4], red2[4];
  if ((tid & 63) == 0) { red1[tid >> 6] = s; red2[tid >> 6] = ss; }
  __syncthreads();
  s = red1[0] + red1[1] + red1[2] + red1[3];
  ss = red2[0] + red2[1] + red2[2] + red2[3];
  const float mu = s * (1.0f / 1024.0f);
  const float var = ss * (1.0f / 1024.0f) - mu * mu;
  const float rstd = 1.0f / sqrtf(var + 1e-5f);
  const float4 wv = *reinterpret_cast<const float4*>(&w[tid * 4]);
  float4 o;
  o.x = (v.x - mu) * rstd * wv.x;
  o.y = (v.y - mu) * rstd * wv.y;
  o.z = (v.z - mu) * rstd * wv.z;
  o.w = (v.w - mu) * rstd * wv.w;
  *reinterpret_cast<float4*>(&out[(size_t)t * 1024 + tid * 4]) = o;
}

// ---------- high-precision GEMM: C = [clip]( A(MxK) @ B(KxN) ) [+ Res]
__global__ __launch_bounds__(256) void gemm_split3_kernel(
    const float* __restrict__ A, const float* __restrict__ B,
    float* __restrict__ C, const float* __restrict__ Res,
    int N, int K, int doclip) {
  __shared__ alignas(16) unsigned short A1[64][40], A2[64][40], A3[64][40];
  __shared__ alignas(16) unsigned short B1[64][40], B2[64][40], B3[64][40];
  const int tid = threadIdx.x;
  const int m0 = blockIdx.x * 64;
  const int n0 = blockIdx.y * 64;
  const int w = tid >> 6, l = tid & 63;
  const int wm = (w >> 1) * 32, wn = (w & 1) * 32;
  const int lr = l & 15, lg = l >> 4;
  const int tkA = tid & 7, tmA = tid >> 3;
  const int tnB = tid & 63, kbB = tid >> 6;

  f32x4 acc[2][2] = {{{0.f,0.f,0.f,0.f},{0.f,0.f,0.f,0.f}},
                     {{0.f,0.f,0.f,0.f},{0.f,0.f,0.f,0.f}}};

  for (int k0 = 0; k0 < K; k0 += 32) {
#pragma unroll
    for (int p = 0; p < 2; ++p) {
      const int m = tmA + p * 32;
      const float4 va = *reinterpret_cast<const float4*>(&A[(size_t)(m0 + m) * K + k0 + tkA * 4]);
      unsigned short h1[4], h2[4], h3[4];
      split3(va.x, h1[0], h2[0], h3[0]);
      split3(va.y, h1[1], h2[1], h3[1]);
      split3(va.z, h1[2], h2[2], h3[2]);
      split3(va.w, h1[3], h2[3], h3[3]);
      *reinterpret_cast<ushort4*>(&A1[m][tkA * 4]) = make_ushort4(h1[0], h1[1], h1[2], h1[3]);
      *reinterpret_cast<ushort4*>(&A2[m][tkA * 4]) = make_ushort4(h2[0], h2[1], h2[2], h2[3]);
      *reinterpret_cast<ushort4*>(&A3[m][tkA * 4]) = make_ushort4(h3[0], h3[1], h3[2], h3[3]);
    }
    {
      unsigned short b1[8], b2[8], b3[8];
#pragma unroll
      for (int j = 0; j < 8; ++j) {
        const float vb = B[(size_t)(k0 + kbB * 8 + j) * N + n0 + tnB];
        split3(vb, b1[j], b2[j], b3[j]);
      }
      *reinterpret_cast<ushort4*>(&B1[tnB][kbB * 8])     = make_ushort4(b1[0], b1[1], b1[2], b1[3]);
      *reinterpret_cast<ushort4*>(&B1[tnB][kbB * 8 + 4]) = make_ushort4(b1[4], b1[5], b1[6], b1[7]);
      *reinterpret_cast<ushort4*>(&B2[tnB][kbB * 8])     = make_ushort4(b2[0], b2[1], b2[2], b2[3]);
      *reinterpret_cast<ushort4*>(&B2[tnB][kbB * 8 + 4]) = make_ushort4(b2[4], b2[5], b2[6], b2[7]);
      *reinterpret_cast<ushort4*>(&B3[tnB][kbB * 8])     = make_ushort4(b3[0], b3[1], b3[2], b3[3]);
      *reinterpret_cast<ushort4*>(&B3[tnB][kbB * 8 + 4]) = make_ushort4(b3[4], b3[5], b3[6], b3[7]);
    }
    __syncthreads();
    bfrag af[2][3], bg[2][3];
#pragma unroll
    for (int mi = 0; mi < 2; ++mi) {
      const int ar = wm + mi * 16 + lr;
      af[mi][0] = *reinterpret_cast<const bfrag*>(&A1[ar][lg * 8]);
      af[mi][1] = *reinterpret_cast<const bfrag*>(&A2[ar][lg * 8]);
      af[mi][2] = *reinterpret_cast<const bfrag*>(&A3[ar][lg * 8]);
    }
#pragma unroll
    for (int ni = 0; ni < 2; ++ni) {
      const int br = wn + ni * 16 + lr;
      bg[ni][0] = *reinterpret_cast<const bfrag*>(&B1[br][lg * 8]);
      bg[ni][1] = *reinterpret_cast<const bfrag*>(&B2[br][lg * 8]);
      bg[ni][2] = *reinterpret_cast<const bfrag*>(&B3[br][lg * 8]);
    }
#pragma unroll
    for (int mi = 0; mi < 2; ++mi)
#pragma unroll
      for (int ni = 0; ni < 2; ++ni) {
        f32x4 c = acc[mi][ni];
        c = __builtin_amdgcn_mfma_f32_16x16x32_bf16(af[mi][2], bg[ni][0], c, 0, 0, 0);
        c = __builtin_amdgcn_mfma_f32_16x16x32_bf16(af[mi][1], bg[ni][1], c, 0, 0, 0);
        c = __builtin_amdgcn_mfma_f32_16x16x32_bf16(af[mi][0], bg[ni][2], c, 0, 0, 0);
        c = __builtin_amdgcn_mfma_f32_16x16x32_bf16(af[mi][1], bg[ni][0], c, 0, 0, 0);
        c = __builtin_amdgcn_mfma_f32_16x16x32_bf16(af[mi][0], bg[ni][1], c, 0, 0, 0);
        c = __builtin_amdgcn_mfma_f32_16x16x32_bf16(af[mi][0], bg[ni][0], c, 0, 0, 0);
        acc[mi][ni] = c;
      }
    __syncthreads();
  }
#pragma unroll
  for (int mi = 0; mi < 2; ++mi)
#pragma unroll
    for (int ni = 0; ni < 2; ++ni)
#pragma unroll
      for (int r = 0; r < 4; ++r) {
        const int row = m0 + wm + mi * 16 + lg * 4 + r;
        const int col = n0 + wn + ni * 16 + lr;
        float vv = acc[mi][ni][r];
        if (doclip) vv = fminf(fmaxf(vv, -8.0f), 8.0f);
        if (Res) vv += Res[(size_t)row * N + col];
        C[(size_t)row * N + col] = vv;
      }
}

// ---------- RoPE table (f64 trig, computed once) ----------
__global__ void rope_table_kernel(const int* __restrict__ posids,
                                  float* __restrict__ cosT, float* __restrict__ sinT) {
  const int t = blockIdx.x * 8 + (threadIdx.x >> 5);
  const int i = threadIdx.x & 31;
  const double ang = (double)posids[t] * pow(500000.0, -(double)i / 32.0);
  cosT[t * 32 + i] = (float)cos(ang);
  sinT[t * 32 + i] = (float)sin(ang);
}

// ---------- RoPE apply on q (T,16,64) and k (T,4,64) ----------
__global__ void rope_kernel(float* __restrict__ q, float* __restrict__ k,
                            const float* __restrict__ cosT, const float* __restrict__ sinT) {
  const int t = blockIdx.x;
  const int hh = blockIdx.y;   // 0..19: 16 q heads then 4 k heads
  const int i = threadIdx.x;   // 0..31
  float* ptr = (hh < 16) ? &q[((size_t)t * 16 + hh) * 64]
                         : &k[((size_t)t * 4 + (hh - 16)) * 64];
  const float c = cosT[t * 32 + i], s = sinT[t * 32 + i];
  const float u1 = ptr[i], u2 = ptr[i + 32];
  ptr[i]      = u1 * c - u2 * s;
  ptr[i + 32] = u2 * c + u1 * s;
}

// ---------- prep: split-2 bf16 K (row-major) and V (transposed) ----------
__global__ __launch_bounds__(256) void prep_kv_kernel(
    const float* __restrict__ k, const float* __restrict__ v,
    unsigned short* __restrict__ Kp1, unsigned short* __restrict__ Kp2,
    unsigned short* __restrict__ Vp1, unsigned short* __restrict__ Vp2) {
  const int key = blockIdx.x;          // 0..1023
  const int kvh = threadIdx.x >> 6;    // 0..3
  const int d = threadIdx.x & 63;
  const float kk = k[((size_t)key * 4 + kvh) * 64 + d];
  const float vv = v[((size_t)key * 4 + kvh) * 64 + d];
  unsigned short a1, a2, b1, b2;
  split2(kk, a1, a2);
  split2(vv, b1, b2);
  const size_t ki = ((size_t)kvh * 1024 + key) * 64 + d;
  Kp1[ki] = a1; Kp2[ki] = a2;
  const size_t vi = ((size_t)kvh * 64 + d) * 1024 + key;
  Vp1[vi] = b1; Vp2[vi] = b2;
}

// ---------- causal GQA flash attention, split-2 bf16 MFMA ----------
__global__ __launch_bounds__(256) void attn_kernel(
    const float* __restrict__ q,
    const unsigned short* __restrict__ Kp1, const unsigned short* __restrict__ Kp2,
    const unsigned short* __restrict__ Vp1, const unsigned short* __restrict__ Vp2,
    float* __restrict__ o) {
  const int qt = blockIdx.x, h = blockIdx.y, kvh = h >> 2;
  __shared__ unsigned short Ks1[64][72], Ks2[64][72], Vt1[64][72], Vt2[64][72];
  __shared__ unsigned short Ps1[4][16][72], Ps2[4][16][72];
  const int tid = threadIdx.x;
  const int w = tid >> 6, l = tid & 63;
  const int lr = l & 15, lg = l >> 4;

  bfrag aq1[2], aq2[2];
  {
    const int tq = qt * 64 + w * 16 + lr;
    const float* qrow = &q[((size_t)tq * 16 + h) * 64];
#pragma unroll
    for (int ks = 0; ks < 2; ++ks) {
      const int d0 = ks * 32 + lg * 8;
      const float4 f0 = *reinterpret_cast<const float4*>(qrow + d0);
      const float4 f1 = *reinterpret_cast<const float4*>(qrow + d0 + 4);
      const float xv[8] = {f0.x, f0.y, f0.z, f0.w, f1.x, f1.y, f1.z, f1.w};
#pragma unroll
      for (int j = 0; j < 8; ++j) {
        const float xs = xv[j] * 0.125f;
        unsigned short p1, p2;
        split2(xs, p1, p2);
        aq1[ks][j] = (short)p1;
        aq2[ks][j] = (short)p2;
      }
    }
  }

  f32x4 accO[4] = {{0.f,0.f,0.f,0.f},{0.f,0.f,0.f,0.f},{0.f,0.f,0.f,0.f},{0.f,0.f,0.f,0.f}};
  float mrun[4] = {-INFINITY, -INFINITY, -INFINITY, -INFINITY};
  float lrun[4] = {0.f, 0.f, 0.f, 0.f};

  for (int ti = 0; ti <= qt; ++ti) {
    const int s0 = ti * 64;
    {
      const size_t kbase = ((size_t)kvh * 1024 + s0 + l) * 64 + w * 16;
      *reinterpret_cast<u16x8*>(&Ks1[l][w * 16])     = *reinterpret_cast<const u16x8*>(&Kp1[kbase]);
      *reinterpret_cast<u16x8*>(&Ks1[l][w * 16 + 8]) = *reinterpret_cast<const u16x8*>(&Kp1[kbase + 8]);
      *reinterpret_cast<u16x8*>(&Ks2[l][w * 16])     = *reinterpret_cast<const u16x8*>(&Kp2[kbase]);
      *reinterpret_cast<u16x8*>(&Ks2[l][w * 16 + 8]) = *reinterpret_cast<const u16x8*>(&Kp2[kbase + 8]);
      const size_t vbase = ((size_t)kvh * 64 + l) * 1024 + s0 + w * 16;
      *reinterpret_cast<u16x8*>(&Vt1[l][w * 16])     = *reinterpret_cast<const u16x8*>(&Vp1[vbase]);
      *reinterpret_cast<u16x8*>(&Vt1[l][w * 16 + 8]) = *reinterpret_cast<const u16x8*>(&Vp1[vbase + 8]);
      *reinterpret_cast<u16x8*>(&Vt2[l][w * 16])     = *reinterpret_cast<const u16x8*>(&Vp2[vbase]);
      *reinterpret_cast<u16x8*>(&Vt2[l][w * 16 + 8]) = *reinterpret_cast<const u16x8*>(&Vp2[vbase + 8]);
    }
    __syncthreads();

    f32x4 accS[4] = {{0.f,0.f,0.f,0.f},{0.f,0.f,0.f,0.f},{0.f,0.f,0.f,0.f},{0.f,0.f,0.f,0.f}};
#pragma unroll
    for (int ks = 0; ks < 2; ++ks) {
      const int koff = ks * 32 + lg * 8;
#pragma unroll
      for (int ni = 0; ni < 4; ++ni) {
        const bfrag b1 = *reinterpret_cast<const bfrag*>(&Ks1[ni * 16 + lr][koff]);
        const bfrag b2 = *reinterpret_cast<const bfrag*>(&Ks2[ni * 16 + lr][koff]);
        f32x4 c = accS[ni];
        c = __builtin_amdgcn_mfma_f32_16x16x32_bf16(aq1[ks], b2, c, 0, 0, 0);
        c = __builtin_amdgcn_mfma_f32_16x16x32_bf16(aq2[ks], b1, c, 0, 0, 0);
        c = __builtin_amdgcn_mfma_f32_16x16x32_bf16(aq1[ks], b1, c, 0, 0, 0);
        accS[ni] = c;
      }
    }
    if (ti == qt) {
      const int rowb = w * 16 + lg * 4;
#pragma unroll
      for (int ni = 0; ni < 4; ++ni)
#pragma unroll
        for (int r = 0; r < 4; ++r)
          if (ni * 16 + lr > rowb + r) accS[ni][r] = -INFINITY;
    }
    float alpha[4];
#pragma unroll
    for (int r = 0; r < 4; ++r) {
      float tm = fmaxf(fmaxf(accS[0][r], accS[1][r]), fmaxf(accS[2][r], accS[3][r]));
      tm = fmaxf(tm, __shfl_xor(tm, 1));
      tm = fmaxf(tm, __shfl_xor(tm, 2));
      tm = fmaxf(tm, __shfl_xor(tm, 4));
      tm = fmaxf(tm, __shfl_xor(tm, 8));
      const float mnew = fmaxf(mrun[r], tm);
      alpha[r] = __expf(mrun[r] - mnew);
      mrun[r] = mnew;
      float ps = 0.f;
#pragma unroll
      for (int ni = 0; ni < 4; ++ni) {
        const float pv = __expf(accS[ni][r] - mnew);
        accS[ni][r] = pv;
        ps += pv;
      }
      ps += __shfl_xor(ps, 1);
      ps += __shfl_xor(ps, 2);
      ps += __shfl_xor(ps, 4);
      ps += __shfl_xor(ps, 8);
      lrun[r] = lrun[r] * alpha[r] + ps;
    }
#pragma unroll
    for (int ni = 0; ni < 4; ++ni)
#pragma unroll
      for (int r = 0; r < 4; ++r) {
        const float pv = accS[ni][r];
        unsigned short p1, p2;
        split2(pv, p1, p2);
        Ps1[w][lg * 4 + r][ni * 16 + lr] = p1;
        Ps2[w][lg * 4 + r][ni * 16 + lr] = p2;
      }
#pragma unroll
    for (int ni = 0; ni < 4; ++ni)
#pragma unroll
      for (int r = 0; r < 4; ++r) accO[ni][r] *= alpha[r];

    asm volatile("s_waitcnt lgkmcnt(0)" ::: "memory");

#pragma unroll
    for (int kk = 0; kk < 2; ++kk) {
      const int koff = kk * 32 + lg * 8;
      const bfrag pa1 = *reinterpret_cast<const bfrag*>(&Ps1[w][lr][koff]);
      const bfrag pa2 = *reinterpret_cast<const bfrag*>(&Ps2[w][lr][koff]);
#pragma unroll
      for (int ni = 0; ni < 4; ++ni) {
        const bfrag vb1 = *reinterpret_cast<const bfrag*>(&Vt1[ni * 16 + lr][koff]);
        const bfrag vb2 = *reinterpret_cast<const bfrag*>(&Vt2[ni * 16 + lr][koff]);
        f32x4 c = accO[ni];
        c = __builtin_amdgcn_mfma_f32_16x16x32_bf16(pa1, vb2, c, 0, 0, 0);
        c = __builtin_amdgcn_mfma_f32_16x16x32_bf16(pa2, vb1, c, 0, 0, 0);
        c = __builtin_amdgcn_mfma_f32_16x16x32_bf16(pa1, vb1, c, 0, 0, 0);
        accO[ni] = c;
      }
    }
    __syncthreads();
  }

  const int tqo = qt * 64 + w * 16 + lg * 4;
#pragma unroll
  for (int r = 0; r < 4; ++r) {
    const float inv = 1.0f / lrun[r];
#pragma unroll
    for (int ni = 0; ni < 4; ++ni)
      o[((size_t)(tqo + r) * 16 + h) * 64 + ni * 16 + lr] = accO[ni][r] * inv;
  }
}

// ---------- router: top-2 of softmax(h2 @ Wr) ----------
__global__ __launch_bounds__(64) void router_kernel(const float* __restrict__ h2,
                                                    const float* __restrict__ Wr,
                                                    int* __restrict__ eidx,
                                                    float* __restrict__ egate) {
  const int t = blockIdx.x;
  const int l = threadIdx.x;
  float p[8];
#pragma unroll
  for (int e = 0; e < 8; ++e) p[e] = 0.f;
  for (int d = l; d < 1024; d += 64) {
    const float x = h2[(size_t)t * 1024 + d];
    const float4 w0 = *reinterpret_cast<const float4*>(&Wr[d * 8]);
    const float4 w1 = *reinterpret_cast<const float4*>(&Wr[d * 8 + 4]);
    p[0] += x * w0.x; p[1] += x * w0.y; p[2] += x * w0.z; p[3] += x * w0.w;
    p[4] += x * w1.x; p[5] += x * w1.y; p[6] += x * w1.z; p[7] += x * w1.w;
  }
#pragma unroll
  for (int off = 32; off; off >>= 1) {
#pragma unroll
    for (int e = 0; e < 8; ++e) p[e] += __shfl_xor(p[e], off);
  }
  if (l == 0) {
    int i0 = 0; float b0 = p[0];
#pragma unroll
    for (int e = 1; e < 8; ++e) if (p[e] > b0) { b0 = p[e]; i0 = e; }
    int i1 = -1; float b1 = -INFINITY;
#pragma unroll
    for (int e = 0; e < 8; ++e) if (e != i0 && p[e] > b1) { b1 = p[e]; i1 = e; }
    const float ex = expf(b1 - b0);
    eidx[t * 2] = i0; eidx[t * 2 + 1] = i1;
    egate[t * 2] = 1.0f / (1.0f + ex);
    egate[t * 2 + 1] = ex / (1.0f + ex);
  }
}

// ---------- dispatch: replicate jnp cumsum slot assignment ----------
__global__ __launch_bounds__(256) void dispatch_kernel(
    const int* __restrict__ eidx, int* __restrict__ cnt,
    int* __restrict__ slot_token, int* __restrict__ entry_slot) {
  __shared__ unsigned char ef[2048];
  __shared__ unsigned short ch[256][8];
  const int tid = threadIdx.x;
  for (int i = tid; i < 2048; i += 256) ef[i] = (unsigned char)eidx[i];
  __syncthreads();
  int loc[8];
#pragma unroll
  for (int e = 0; e < 8; ++e) loc[e] = 0;
  const int base = tid * 8;
  for (int j = 0; j < 8; ++j) {
    const int ee = ef[base + j];
#pragma unroll
    for (int e = 0; e < 8; ++e) loc[e] += (ee == e);
  }
#pragma unroll
  for (int e = 0; e < 8; ++e) ch[tid][e] = (unsigned short)loc[e];
  __syncthreads();
  int pre[8];
#pragma unroll
  for (int e = 0; e < 8; ++e) pre[e] = 0;
  for (int t2 = 0; t2 < tid; ++t2) {
#pragma unroll
    for (int e = 0; e < 8; ++e) pre[e] += ch[t2][e];
  }
  if (tid == 255) {
#pragma unroll
    for (int e = 0; e < 8; ++e) cnt[e] = min(pre[e] + loc[e], 512);
  }
  for (int j = 0; j < 8; ++j) {
    const int i = base + j;
    const int ee = ef[i];
    int slot = 0;
#pragma unroll
    for (int e = 0; e < 8; ++e) {
      if (e == ee) { slot = pre[e]; pre[e] = pre[e] + 1; }
    }
    if (slot < 512) {
      slot_token[ee * 512 + slot] = i >> 1;
      entry_slot[i] = slot;
    } else {
      entry_slot[i] = -1;
    }
  }
}

// ---------- pre-convert dispatched tokens to bf16: xbf[e][slot][1024] ----------
__global__ __launch_bounds__(256) void moe_xbf_kernel(
    const float* __restrict__ h2, const int* __restrict__ cnt,
    const int* __restrict__ slot_token, unsigned short* __restrict__ xbf) {
  const int row = blockIdx.x;          // e*512 + slot
  const int e = row >> 9, slot = row & 511;
  const int tid = threadIdx.x;
  ushort4 o;
  if (slot < cnt[e]) {
    const int tok = slot_token[row];
    const float4 f = *reinterpret_cast<const float4*>(&h2[(size_t)tok * 1024 + tid * 4]);
    o = make_ushort4(bf16_rne(f.x), bf16_rne(f.y), bf16_rne(f.z), bf16_rne(f.w));
  } else {
    o = make_ushort4(0, 0, 0, 0);
  }
  *reinterpret_cast<ushort4*>(&xbf[(size_t)row * 1024 + tid * 4]) = o;
}

// ---------- MoE pass 1 (one-weight-pass, BK=64): act = silu(X@Wg)*(X@Wu) ----------
// grid (nt=64 [BN=32], e=8); BM=256 with in-block m-chunk loop
__global__ __launch_bounds__(256, 2) void moe_mlp1_kernel(
    const unsigned short* __restrict__ xbf, const float* __restrict__ Wg,
    const float* __restrict__ Wu, const int* __restrict__ cnt,
    unsigned short* __restrict__ act) {
  const int nt = blockIdx.x, e = blockIdx.y;
  const int n0 = nt * 32;
  const int ce = cnt[e];
  if (ce <= 0) return;
  __shared__ alignas(16) unsigned short As[256][72];
  __shared__ alignas(16) unsigned short Bg[32][72], Bu[32][72];
  const int tid = threadIdx.x;
  const int w = tid >> 6, l = tid & 63;
  const int lr = l & 15, lg = l >> 4;
  const int wc = tid & 31, kq8 = tid >> 5;     // weight staging: col, k-octet
  const float* WgE = Wg + (size_t)e * 1024 * 2048 + n0;
  const float* WuE = Wu + (size_t)e * 1024 * 2048 + n0;
  const unsigned short* xbE = xbf + (size_t)e * 512 * 1024;
  const int nchunk = (ce + 255) >> 8;

  for (int mc = 0; mc < nchunk; ++mc) {
    const unsigned short* arow = &xbE[(size_t)(mc * 256 + tid) * 1024];
    f32x4 accG[4][2], accU[4][2];
#pragma unroll
    for (int mi = 0; mi < 4; ++mi)
#pragma unroll
      for (int ni = 0; ni < 2; ++ni) {
        accG[mi][ni] = (f32x4){0.f, 0.f, 0.f, 0.f};
        accU[mi][ni] = (f32x4){0.f, 0.f, 0.f, 0.f};
      }

    for (int k0 = 0; k0 < 1024; k0 += 64) {
      // ---- stage A: thread = one token row, 64 k (pure copies) ----
#pragma unroll
      for (int j = 0; j < 8; ++j)
        *reinterpret_cast<u16x8*>(&As[tid][j * 8]) =
            *reinterpret_cast<const u16x8*>(&arow[k0 + j * 8]);
      // ---- stage weights (64k x 32n each) ----
      {
        u16x8 g8, u8;
#pragma unroll
        for (int j = 0; j < 8; ++j) {
          const size_t off = (size_t)(k0 + kq8 * 8 + j) * 2048 + wc;
          g8[j] = bf16_rne(WgE[off]);
          u8[j] = bf16_rne(WuE[off]);
        }
        *reinterpret_cast<u16x8*>(&Bg[wc][kq8 * 8]) = g8;
        *reinterpret_cast<u16x8*>(&Bu[wc][kq8 * 8]) = u8;
      }
      __syncthreads();
      bfrag af[4][2], bgf[2][2], buf2[2][2];
#pragma unroll
      for (int mi = 0; mi < 4; ++mi)
#pragma unroll
        for (int kf = 0; kf < 2; ++kf)
          af[mi][kf] = *reinterpret_cast<const bfrag*>(&As[w * 64 + mi * 16 + lr][kf * 32 + lg * 8]);
#pragma unroll
      for (int ni = 0; ni < 2; ++ni)
#pragma unroll
        for (int kf = 0; kf < 2; ++kf) {
          bgf[ni][kf]  = *reinterpret_cast<const bfrag*>(&Bg[ni * 16 + lr][kf * 32 + lg * 8]);
          buf2[ni][kf] = *reinterpret_cast<const bfrag*>(&Bu[ni * 16 + lr][kf * 32 + lg * 8]);
        }
#pragma unroll
      for (int mi = 0; mi < 4; ++mi)
#pragma unroll
        for (int ni = 0; ni < 2; ++ni)
#pragma unroll
          for (int kf = 0; kf < 2; ++kf) {
            accG[mi][ni] = __builtin_amdgcn_mfma_f32_16x16x32_bf16(af[mi][kf], bgf[ni][kf], accG[mi][ni], 0, 0, 0);
            accU[mi][ni] = __builtin_amdgcn_mfma_f32_16x16x32_bf16(af[mi][kf], buf2[ni][kf], accU[mi][ni], 0, 0, 0);
          }
      __syncthreads();
    }
    // ---- epilogue ----
#pragma unroll
    for (int mi = 0; mi < 4; ++mi) {
      const int mlocal = w * 64 + mi * 16 + lg * 4;
#pragma unroll
      for (int r = 0; r < 4; ++r) {
        const int m = mc * 256 + mlocal + r;
        if (m < ce) {
#pragma unroll
          for (int ni = 0; ni < 2; ++ni) {
            const int col = n0 + ni * 16 + lr;
            const float gg = accG[mi][ni][r];
            const float uu = accU[mi][ni][r];
            const float a = gg / (1.0f + __expf(-gg)) * uu;
            act[((size_t)e * 512 + m) * 2048 + col] = bf16_rne(a);
          }
        }
      }
    }
  }
}

// ---------- MoE pass 2 (one-weight-pass, BK=64, split-K=2): ob_part = act @ Wd ----------
// grid (nt=32 [BN=32], e=8, kc=2); BM=256 with in-block m-chunk loop
__global__ __launch_bounds__(256, 2) void moe_mlp2_kernel(
    const unsigned short* __restrict__ act, const float* __restrict__ Wd,
    const int* __restrict__ cnt, float* __restrict__ ob) {
  const int nt = blockIdx.x, e = blockIdx.y, kc = blockIdx.z;
  const int n0 = nt * 32;
  const int ce = cnt[e];
  if (ce <= 0) return;
  __shared__ alignas(16) unsigned short As[256][72];
  __shared__ alignas(16) unsigned short Bs[32][72];
  const int tid = threadIdx.x;
  const int w = tid >> 6, l = tid & 63;
  const int lr = l & 15, lg = l >> 4;
  const int wc = tid & 31, kq8 = tid >> 5;
  const unsigned short* actE = act + (size_t)e * 512 * 2048;
  const float* WdE = Wd + (size_t)e * 2048 * 1024 + n0;
  float* obE = ob + (size_t)kc * 8 * 512 * 1024;
  const int kbeg = kc * 1024, kend = kbeg + 1024;
  const int nchunk = (ce + 255) >> 8;

  for (int mc = 0; mc < nchunk; ++mc) {
    const int mrow = mc * 256 + tid;
    f32x4 acc[4][2];
#pragma unroll
    for (int mi = 0; mi < 4; ++mi)
#pragma unroll
      for (int ni = 0; ni < 2; ++ni) acc[mi][ni] = (f32x4){0.f, 0.f, 0.f, 0.f};

    for (int k0 = kbeg; k0 < kend; k0 += 64) {
      // ---- stage A (bf16 copies) ----
#pragma unroll
      for (int j = 0; j < 8; ++j)
        *reinterpret_cast<u16x8*>(&As[tid][j * 8]) =
            *reinterpret_cast<const u16x8*>(&actE[(size_t)mrow * 2048 + k0 + j * 8]);
      // ---- stage Wd (64k x 32n) ----
      {
        u16x8 d8;
#pragma unroll
        for (int j = 0; j < 8; ++j)
          d8[j] = bf16_rne(WdE[(size_t)(k0 + kq8 * 8 + j) * 1024 + wc]);
        *reinterpret_cast<u16x8*>(&Bs[wc][kq8 * 8]) = d8;
      }
      __syncthreads();
      bfrag af[4][2], bf2[2][2];
#pragma unroll
      for (int mi = 0; mi < 4; ++mi)
#pragma unroll
        for (int kf = 0; kf < 2; ++kf)
          af[mi][kf] = *reinterpret_cast<const bfrag*>(&As[w * 64 + mi * 16 + lr][kf * 32 + lg * 8]);
#pragma unroll
      for (int ni = 0; ni < 2; ++ni)
#pragma unroll
        for (int kf = 0; kf < 2; ++kf)
          bf2[ni][kf] = *reinterpret_cast<const bfrag*>(&Bs[ni * 16 + lr][kf * 32 + lg * 8]);
#pragma unroll
      for (int mi = 0; mi < 4; ++mi)
#pragma unroll
        for (int ni = 0; ni < 2; ++ni)
#pragma unroll
          for (int kf = 0; kf < 2; ++kf)
            acc[mi][ni] = __builtin_amdgcn_mfma_f32_16x16x32_bf16(af[mi][kf], bf2[ni][kf], acc[mi][ni], 0, 0, 0);
      __syncthreads();
    }
#pragma unroll
    for (int mi = 0; mi < 4; ++mi) {
      const int mlocal = w * 64 + mi * 16 + lg * 4;
#pragma unroll
      for (int r = 0; r < 4; ++r) {
        const int m = mc * 256 + mlocal + r;
        if (m < ce) {
#pragma unroll
          for (int ni = 0; ni < 2; ++ni)
            obE[((size_t)e * 512 + m) * 1024 + n0 + ni * 16 + lr] = acc[mi][ni][r];
        }
      }
    }
  }
}

// ---------- combine: out += sum_k gate * (ob0+ob1)[e_k][slot_k] ----------
__global__ __launch_bounds__(256) void combine_kernel(
    const float* __restrict__ ob, const int* __restrict__ eidx,
    const float* __restrict__ egate, const int* __restrict__ entry_slot,
    float* __restrict__ out) {
  const int t = blockIdx.x;
  const int d = threadIdx.x * 4;
  const size_t half = (size_t)8 * 512 * 1024;
  float4 o4 = *reinterpret_cast<float4*>(&out[(size_t)t * 1024 + d]);
#pragma unroll
  for (int kk = 0; kk < 2; ++kk) {
    const int i = t * 2 + kk;
    const int s = entry_slot[i];
    if (s >= 0) {
      const int e = eidx[i];
      const float g = egate[i];
      const size_t base = ((size_t)e * 512 + s) * 1024 + d;
      const float4 c0 = *reinterpret_cast<const float4*>(&ob[base]);
      const float4 c1 = *reinterpret_cast<const float4*>(&ob[half + base]);
      o4.x += g * (c0.x + c1.x); o4.y += g * (c0.y + c1.y);
      o4.z += g * (c0.z + c1.z); o4.w += g * (c0.w + c1.w);
    }
  }
  *reinterpret_cast<float4*>(&out[(size_t)t * 1024 + d]) = o4;
}

extern "C" void kernel_launch(void* const* d_in, const int* in_sizes, int n_in,
                              void* d_out, int out_size, void* d_ws, size_t ws_size,
                              hipStream_t stream) {
  const float* hidden = (const float*)d_in[0];
  const int* posids  = (const int*)d_in[1];
  const float* ln1w  = (const float*)d_in[2];
  const float* ln2w  = (const float*)d_in[3];
  const float* Wq    = (const float*)d_in[4];
  const float* Wk    = (const float*)d_in[5];
  const float* Wv    = (const float*)d_in[6];
  const float* Wo    = (const float*)d_in[7];
  const float* Wr    = (const float*)d_in[8];
  const float* Wg    = (const float*)d_in[9];
  const float* Wu    = (const float*)d_in[10];
  const float* Wd    = (const float*)d_in[11];
  float* out = (float*)d_out;

  char* p = (char*)d_ws;
  auto alloc = [&](size_t bytes) { char* r = p; p += (bytes + 255) & ~(size_t)255; return r; };
  float* h1   = (float*)alloc((size_t)1024 * 1024 * 4);
  float* qb   = (float*)alloc((size_t)1024 * 1024 * 4);
  float* kb   = (float*)alloc((size_t)1024 * 256 * 4);
  float* vb   = (float*)alloc((size_t)1024 * 256 * 4);
  float* ao   = (float*)alloc((size_t)1024 * 1024 * 4);
  float* h2   = (float*)alloc((size_t)1024 * 1024 * 4);
  unsigned short* act = (unsigned short*)alloc((size_t)8 * 512 * 2048 * 2);
  float* obuf = (float*)alloc((size_t)2 * 8 * 512 * 1024 * 4);
  int* eidx   = (int*)alloc(2048 * 4);
  float* egate = (float*)alloc(2048 * 4);
  int* cnt    = (int*)alloc(8 * 4);
  int* slot_token = (int*)alloc((size_t)8 * 512 * 4);
  int* entry_slot = (int*)alloc(2048 * 4);
  float* cosT = (float*)alloc((size_t)1024 * 32 * 4);
  float* sinT = (float*)alloc((size_t)1024 * 32 * 4);
  unsigned short* Kp1 = (unsigned short*)alloc((size_t)4 * 1024 * 64 * 2);
  unsigned short* Kp2 = (unsigned short*)alloc((size_t)4 * 1024 * 64 * 2);
  unsigned short* Vp1 = (unsigned short*)alloc((size_t)4 * 1024 * 64 * 2);
  unsigned short* Vp2 = (unsigned short*)alloc((size_t)4 * 1024 * 64 * 2);
  unsigned short* xbf = (unsigned short*)alloc((size_t)8 * 512 * 1024 * 2);

  rope_table_kernel<<<128, 256, 0, stream>>>(posids, cosT, sinT);
  ln_kernel<<<1024, 256, 0, stream>>>(hidden, ln1w, h1);
  gemm_split3_kernel<<<dim3(16, 16), 256, 0, stream>>>(h1, Wq, qb, nullptr, 1024, 1024, 1);
  gemm_split3_kernel<<<dim3(16, 4), 256, 0, stream>>>(h1, Wk, kb, nullptr, 256, 1024, 1);
  gemm_split3_kernel<<<dim3(16, 4), 256, 0, stream>>>(h1, Wv, vb, nullptr, 256, 1024, 1);
  rope_kernel<<<dim3(1024, 20), 32, 0, stream>>>(qb, kb, cosT, sinT);
  prep_kv_kernel<<<1024, 256, 0, stream>>>(kb, vb, Kp1, Kp2, Vp1, Vp2);
  attn_kernel<<<dim3(16, 16), 256, 0, stream>>>(qb, Kp1, Kp2, Vp1, Vp2, ao);
  gemm_split3_kernel<<<dim3(16, 16), 256, 0, stream>>>(ao, Wo, out, hidden, 1024, 1024, 0);
  ln_kernel<<<1024, 256, 0, stream>>>(out, ln2w, h2);
  router_kernel<<<1024, 64, 0, stream>>>(h2, Wr, eidx, egate);
  dispatch_kernel<<<1, 256, 0, stream>>>(eidx, cnt, slot_token, entry_slot);
  moe_xbf_kernel<<<4096, 256, 0, stream>>>(h2, cnt, slot_token, xbf);
  moe_mlp1_kernel<<<dim3(64, 8), 256, 0, stream>>>(xbf, Wg, Wu, cnt, act);
  moe_mlp2_kernel<<<dim3(32, 8, 2), 256, 0, stream>>>(act, Wd, cnt, obuf);
  combine_kernel<<<1024, 256, 0, stream>>>(obuf, eidx, egate, entry_slot, out);
}

// Round 5
// 383.829 us; speedup vs baseline: 1.7491x; 1.1536x over previous
//
#include <hip/hip_runtime.h>
#include <math.h>

typedef __attribute__((ext_vector_type(8))) short bfrag;   // 8 x bf16 bits
typedef __attribute__((ext_vector_type(8))) unsigned short u16x8;
typedef __attribute__((ext_vector_type(4))) float f32x4;   // MFMA accumulator

// ---------- bf16 helpers ----------
__device__ __forceinline__ unsigned short bf16_rne(float f) {
  unsigned int u = __float_as_uint(f);
  u += 0x7FFFu + ((u >> 16) & 1u);
  return (unsigned short)(u >> 16);
}
__device__ __forceinline__ float bf16f(unsigned short h) {
  return __uint_as_float(((unsigned int)h) << 16);
}
__device__ __forceinline__ void split3(float x, unsigned short &o1, unsigned short &o2, unsigned short &o3) {
  o1 = bf16_rne(x);
  const float r1 = x - bf16f(o1);
  o2 = bf16_rne(r1);
  const float r2 = r1 - bf16f(o2);
  o3 = bf16_rne(r2);
}
__device__ __forceinline__ void split2(float x, unsigned short &o1, unsigned short &o2) {
  o1 = bf16_rne(x);
  o2 = bf16_rne(x - bf16f(o1));
}

// ---------- LayerNorm (row = 1024 f32) ----------
__global__ __launch_bounds__(256) void ln_kernel(const float* __restrict__ x,
                                                 const float* __restrict__ w,
                                                 float* __restrict__ out) {
  const int t = blockIdx.x;
  const int tid = threadIdx.x;
  const float4 v = *reinterpret_cast<const float4*>(&x[(size_t)t * 1024 + tid * 4]);
  float s = v.x + v.y + v.z + v.w;
  float ss = v.x * v.x + v.y * v.y + v.z * v.z + v.w * v.w;
#pragma unroll
  for (int off = 32; off; off >>= 1) {
    s += __shfl_xor(s, off);
    ss += __shfl_xor(ss, off);
  }
  __shared__ float red1[4], red2[4];
  if ((tid & 63) == 0) { red1[tid >> 6] = s; red2[tid >> 6] = ss; }
  __syncthreads();
  s = red1[0] + red1[1] + red1[2] + red1[3];
  ss = red2[0] + red2[1] + red2[2] + red2[3];
  const float mu = s * (1.0f / 1024.0f);
  const float var = ss * (1.0f / 1024.0f) - mu * mu;
  const float rstd = 1.0f / sqrtf(var + 1e-5f);
  const float4 wv = *reinterpret_cast<const float4*>(&w[tid * 4]);
  float4 o;
  o.x = (v.x - mu) * rstd * wv.x;
  o.y = (v.y - mu) * rstd * wv.y;
  o.z = (v.z - mu) * rstd * wv.z;
  o.w = (v.w - mu) * rstd * wv.w;
  *reinterpret_cast<float4*>(&out[(size_t)t * 1024 + tid * 4]) = o;
}

// ---------- high-precision GEMM: C = [clip]( A(MxK) @ B(KxN) ) [+ Res]
__global__ __launch_bounds__(256) void gemm_split3_kernel(
    const float* __restrict__ A, const float* __restrict__ B,
    float* __restrict__ C, const float* __restrict__ Res,
    int N, int K, int doclip) {
  __shared__ alignas(16) unsigned short A1[64][40], A2[64][40], A3[64][40];
  __shared__ alignas(16) unsigned short B1[64][40], B2[64][40], B3[64][40];
  const int tid = threadIdx.x;
  const int m0 = blockIdx.x * 64;
  const int n0 = blockIdx.y * 64;
  const int w = tid >> 6, l = tid & 63;
  const int wm = (w >> 1) * 32, wn = (w & 1) * 32;
  const int lr = l & 15, lg = l >> 4;
  const int tkA = tid & 7, tmA = tid >> 3;
  const int tnB = tid & 63, kbB = tid >> 6;

  f32x4 acc[2][2] = {{{0.f,0.f,0.f,0.f},{0.f,0.f,0.f,0.f}},
                     {{0.f,0.f,0.f,0.f},{0.f,0.f,0.f,0.f}}};

  for (int k0 = 0; k0 < K; k0 += 32) {
#pragma unroll
    for (int p = 0; p < 2; ++p) {
      const int m = tmA + p * 32;
      const float4 va = *reinterpret_cast<const float4*>(&A[(size_t)(m0 + m) * K + k0 + tkA * 4]);
      unsigned short h1[4], h2[4], h3[4];
      split3(va.x, h1[0], h2[0], h3[0]);
      split3(va.y, h1[1], h2[1], h3[1]);
      split3(va.z, h1[2], h2[2], h3[2]);
      split3(va.w, h1[3], h2[3], h3[3]);
      *reinterpret_cast<ushort4*>(&A1[m][tkA * 4]) = make_ushort4(h1[0], h1[1], h1[2], h1[3]);
      *reinterpret_cast<ushort4*>(&A2[m][tkA * 4]) = make_ushort4(h2[0], h2[1], h2[2], h2[3]);
      *reinterpret_cast<ushort4*>(&A3[m][tkA * 4]) = make_ushort4(h3[0], h3[1], h3[2], h3[3]);
    }
    {
      unsigned short b1[8], b2[8], b3[8];
#pragma unroll
      for (int j = 0; j < 8; ++j) {
        const float vb = B[(size_t)(k0 + kbB * 8 + j) * N + n0 + tnB];
        split3(vb, b1[j], b2[j], b3[j]);
      }
      *reinterpret_cast<ushort4*>(&B1[tnB][kbB * 8])     = make_ushort4(b1[0], b1[1], b1[2], b1[3]);
      *reinterpret_cast<ushort4*>(&B1[tnB][kbB * 8 + 4]) = make_ushort4(b1[4], b1[5], b1[6], b1[7]);
      *reinterpret_cast<ushort4*>(&B2[tnB][kbB * 8])     = make_ushort4(b2[0], b2[1], b2[2], b2[3]);
      *reinterpret_cast<ushort4*>(&B2[tnB][kbB * 8 + 4]) = make_ushort4(b2[4], b2[5], b2[6], b2[7]);
      *reinterpret_cast<ushort4*>(&B3[tnB][kbB * 8])     = make_ushort4(b3[0], b3[1], b3[2], b3[3]);
      *reinterpret_cast<ushort4*>(&B3[tnB][kbB * 8 + 4]) = make_ushort4(b3[4], b3[5], b3[6], b3[7]);
    }
    __syncthreads();
    bfrag af[2][3], bg[2][3];
#pragma unroll
    for (int mi = 0; mi < 2; ++mi) {
      const int ar = wm + mi * 16 + lr;
      af[mi][0] = *reinterpret_cast<const bfrag*>(&A1[ar][lg * 8]);
      af[mi][1] = *reinterpret_cast<const bfrag*>(&A2[ar][lg * 8]);
      af[mi][2] = *reinterpret_cast<const bfrag*>(&A3[ar][lg * 8]);
    }
#pragma unroll
    for (int ni = 0; ni < 2; ++ni) {
      const int br = wn + ni * 16 + lr;
      bg[ni][0] = *reinterpret_cast<const bfrag*>(&B1[br][lg * 8]);
      bg[ni][1] = *reinterpret_cast<const bfrag*>(&B2[br][lg * 8]);
      bg[ni][2] = *reinterpret_cast<const bfrag*>(&B3[br][lg * 8]);
    }
#pragma unroll
    for (int mi = 0; mi < 2; ++mi)
#pragma unroll
      for (int ni = 0; ni < 2; ++ni) {
        f32x4 c = acc[mi][ni];
        c = __builtin_amdgcn_mfma_f32_16x16x32_bf16(af[mi][2], bg[ni][0], c, 0, 0, 0);
        c = __builtin_amdgcn_mfma_f32_16x16x32_bf16(af[mi][1], bg[ni][1], c, 0, 0, 0);
        c = __builtin_amdgcn_mfma_f32_16x16x32_bf16(af[mi][0], bg[ni][2], c, 0, 0, 0);
        c = __builtin_amdgcn_mfma_f32_16x16x32_bf16(af[mi][1], bg[ni][0], c, 0, 0, 0);
        c = __builtin_amdgcn_mfma_f32_16x16x32_bf16(af[mi][0], bg[ni][1], c, 0, 0, 0);
        c = __builtin_amdgcn_mfma_f32_16x16x32_bf16(af[mi][0], bg[ni][0], c, 0, 0, 0);
        acc[mi][ni] = c;
      }
    __syncthreads();
  }
#pragma unroll
  for (int mi = 0; mi < 2; ++mi)
#pragma unroll
    for (int ni = 0; ni < 2; ++ni)
#pragma unroll
      for (int r = 0; r < 4; ++r) {
        const int row = m0 + wm + mi * 16 + lg * 4 + r;
        const int col = n0 + wn + ni * 16 + lr;
        float vv = acc[mi][ni][r];
        if (doclip) vv = fminf(fmaxf(vv, -8.0f), 8.0f);
        if (Res) vv += Res[(size_t)row * N + col];
        C[(size_t)row * N + col] = vv;
      }
}

// ---------- RoPE table (f64 trig, computed once) ----------
__global__ void rope_table_kernel(const int* __restrict__ posids,
                                  float* __restrict__ cosT, float* __restrict__ sinT) {
  const int t = blockIdx.x * 8 + (threadIdx.x >> 5);
  const int i = threadIdx.x & 31;
  const double ang = (double)posids[t] * pow(500000.0, -(double)i / 32.0);
  cosT[t * 32 + i] = (float)cos(ang);
  sinT[t * 32 + i] = (float)sin(ang);
}

// ---------- RoPE apply on q (T,16,64) and k (T,4,64) ----------
__global__ void rope_kernel(float* __restrict__ q, float* __restrict__ k,
                            const float* __restrict__ cosT, const float* __restrict__ sinT) {
  const int t = blockIdx.x;
  const int hh = blockIdx.y;   // 0..19: 16 q heads then 4 k heads
  const int i = threadIdx.x;   // 0..31
  float* ptr = (hh < 16) ? &q[((size_t)t * 16 + hh) * 64]
                         : &k[((size_t)t * 4 + (hh - 16)) * 64];
  const float c = cosT[t * 32 + i], s = sinT[t * 32 + i];
  const float u1 = ptr[i], u2 = ptr[i + 32];
  ptr[i]      = u1 * c - u2 * s;
  ptr[i + 32] = u2 * c + u1 * s;
}

// ---------- prep: split-2 bf16 K (row-major) and V (transposed) ----------
__global__ __launch_bounds__(256) void prep_kv_kernel(
    const float* __restrict__ k, const float* __restrict__ v,
    unsigned short* __restrict__ Kp1, unsigned short* __restrict__ Kp2,
    unsigned short* __restrict__ Vp1, unsigned short* __restrict__ Vp2) {
  const int key = blockIdx.x;          // 0..1023
  const int kvh = threadIdx.x >> 6;    // 0..3
  const int d = threadIdx.x & 63;
  const float kk = k[((size_t)key * 4 + kvh) * 64 + d];
  const float vv = v[((size_t)key * 4 + kvh) * 64 + d];
  unsigned short a1, a2, b1, b2;
  split2(kk, a1, a2);
  split2(vv, b1, b2);
  const size_t ki = ((size_t)kvh * 1024 + key) * 64 + d;
  Kp1[ki] = a1; Kp2[ki] = a2;
  const size_t vi = ((size_t)kvh * 64 + d) * 1024 + key;
  Vp1[vi] = b1; Vp2[vi] = b2;
}

// ---------- causal GQA flash attention, split-2 bf16 MFMA ----------
__global__ __launch_bounds__(256) void attn_kernel(
    const float* __restrict__ q,
    const unsigned short* __restrict__ Kp1, const unsigned short* __restrict__ Kp2,
    const unsigned short* __restrict__ Vp1, const unsigned short* __restrict__ Vp2,
    float* __restrict__ o) {
  const int qt = blockIdx.x, h = blockIdx.y, kvh = h >> 2;
  __shared__ unsigned short Ks1[64][72], Ks2[64][72], Vt1[64][72], Vt2[64][72];
  __shared__ unsigned short Ps1[4][16][72], Ps2[4][16][72];
  const int tid = threadIdx.x;
  const int w = tid >> 6, l = tid & 63;
  const int lr = l & 15, lg = l >> 4;

  bfrag aq1[2], aq2[2];
  {
    const int tq = qt * 64 + w * 16 + lr;
    const float* qrow = &q[((size_t)tq * 16 + h) * 64];
#pragma unroll
    for (int ks = 0; ks < 2; ++ks) {
      const int d0 = ks * 32 + lg * 8;
      const float4 f0 = *reinterpret_cast<const float4*>(qrow + d0);
      const float4 f1 = *reinterpret_cast<const float4*>(qrow + d0 + 4);
      const float xv[8] = {f0.x, f0.y, f0.z, f0.w, f1.x, f1.y, f1.z, f1.w};
#pragma unroll
      for (int j = 0; j < 8; ++j) {
        const float xs = xv[j] * 0.125f;
        unsigned short p1, p2;
        split2(xs, p1, p2);
        aq1[ks][j] = (short)p1;
        aq2[ks][j] = (short)p2;
      }
    }
  }

  f32x4 accO[4] = {{0.f,0.f,0.f,0.f},{0.f,0.f,0.f,0.f},{0.f,0.f,0.f,0.f},{0.f,0.f,0.f,0.f}};
  float mrun[4] = {-INFINITY, -INFINITY, -INFINITY, -INFINITY};
  float lrun[4] = {0.f, 0.f, 0.f, 0.f};

  for (int ti = 0; ti <= qt; ++ti) {
    const int s0 = ti * 64;
    {
      const size_t kbase = ((size_t)kvh * 1024 + s0 + l) * 64 + w * 16;
      *reinterpret_cast<u16x8*>(&Ks1[l][w * 16])     = *reinterpret_cast<const u16x8*>(&Kp1[kbase]);
      *reinterpret_cast<u16x8*>(&Ks1[l][w * 16 + 8]) = *reinterpret_cast<const u16x8*>(&Kp1[kbase + 8]);
      *reinterpret_cast<u16x8*>(&Ks2[l][w * 16])     = *reinterpret_cast<const u16x8*>(&Kp2[kbase]);
      *reinterpret_cast<u16x8*>(&Ks2[l][w * 16 + 8]) = *reinterpret_cast<const u16x8*>(&Kp2[kbase + 8]);
      const size_t vbase = ((size_t)kvh * 64 + l) * 1024 + s0 + w * 16;
      *reinterpret_cast<u16x8*>(&Vt1[l][w * 16])     = *reinterpret_cast<const u16x8*>(&Vp1[vbase]);
      *reinterpret_cast<u16x8*>(&Vt1[l][w * 16 + 8]) = *reinterpret_cast<const u16x8*>(&Vp1[vbase + 8]);
      *reinterpret_cast<u16x8*>(&Vt2[l][w * 16])     = *reinterpret_cast<const u16x8*>(&Vp2[vbase]);
      *reinterpret_cast<u16x8*>(&Vt2[l][w * 16 + 8]) = *reinterpret_cast<const u16x8*>(&Vp2[vbase + 8]);
    }
    __syncthreads();

    f32x4 accS[4] = {{0.f,0.f,0.f,0.f},{0.f,0.f,0.f,0.f},{0.f,0.f,0.f,0.f},{0.f,0.f,0.f,0.f}};
#pragma unroll
    for (int ks = 0; ks < 2; ++ks) {
      const int koff = ks * 32 + lg * 8;
#pragma unroll
      for (int ni = 0; ni < 4; ++ni) {
        const bfrag b1 = *reinterpret_cast<const bfrag*>(&Ks1[ni * 16 + lr][koff]);
        const bfrag b2 = *reinterpret_cast<const bfrag*>(&Ks2[ni * 16 + lr][koff]);
        f32x4 c = accS[ni];
        c = __builtin_amdgcn_mfma_f32_16x16x32_bf16(aq1[ks], b2, c, 0, 0, 0);
        c = __builtin_amdgcn_mfma_f32_16x16x32_bf16(aq2[ks], b1, c, 0, 0, 0);
        c = __builtin_amdgcn_mfma_f32_16x16x32_bf16(aq1[ks], b1, c, 0, 0, 0);
        accS[ni] = c;
      }
    }
    if (ti == qt) {
      const int rowb = w * 16 + lg * 4;
#pragma unroll
      for (int ni = 0; ni < 4; ++ni)
#pragma unroll
        for (int r = 0; r < 4; ++r)
          if (ni * 16 + lr > rowb + r) accS[ni][r] = -INFINITY;
    }
    float alpha[4];
#pragma unroll
    for (int r = 0; r < 4; ++r) {
      float tm = fmaxf(fmaxf(accS[0][r], accS[1][r]), fmaxf(accS[2][r], accS[3][r]));
      tm = fmaxf(tm, __shfl_xor(tm, 1));
      tm = fmaxf(tm, __shfl_xor(tm, 2));
      tm = fmaxf(tm, __shfl_xor(tm, 4));
      tm = fmaxf(tm, __shfl_xor(tm, 8));
      const float mnew = fmaxf(mrun[r], tm);
      alpha[r] = __expf(mrun[r] - mnew);
      mrun[r] = mnew;
      float ps = 0.f;
#pragma unroll
      for (int ni = 0; ni < 4; ++ni) {
        const float pv = __expf(accS[ni][r] - mnew);
        accS[ni][r] = pv;
        ps += pv;
      }
      ps += __shfl_xor(ps, 1);
      ps += __shfl_xor(ps, 2);
      ps += __shfl_xor(ps, 4);
      ps += __shfl_xor(ps, 8);
      lrun[r] = lrun[r] * alpha[r] + ps;
    }
#pragma unroll
    for (int ni = 0; ni < 4; ++ni)
#pragma unroll
      for (int r = 0; r < 4; ++r) {
        const float pv = accS[ni][r];
        unsigned short p1, p2;
        split2(pv, p1, p2);
        Ps1[w][lg * 4 + r][ni * 16 + lr] = p1;
        Ps2[w][lg * 4 + r][ni * 16 + lr] = p2;
      }
#pragma unroll
    for (int ni = 0; ni < 4; ++ni)
#pragma unroll
      for (int r = 0; r < 4; ++r) accO[ni][r] *= alpha[r];

    asm volatile("s_waitcnt lgkmcnt(0)" ::: "memory");

#pragma unroll
    for (int kk = 0; kk < 2; ++kk) {
      const int koff = kk * 32 + lg * 8;
      const bfrag pa1 = *reinterpret_cast<const bfrag*>(&Ps1[w][lr][koff]);
      const bfrag pa2 = *reinterpret_cast<const bfrag*>(&Ps2[w][lr][koff]);
#pragma unroll
      for (int ni = 0; ni < 4; ++ni) {
        const bfrag vb1 = *reinterpret_cast<const bfrag*>(&Vt1[ni * 16 + lr][koff]);
        const bfrag vb2 = *reinterpret_cast<const bfrag*>(&Vt2[ni * 16 + lr][koff]);
        f32x4 c = accO[ni];
        c = __builtin_amdgcn_mfma_f32_16x16x32_bf16(pa1, vb2, c, 0, 0, 0);
        c = __builtin_amdgcn_mfma_f32_16x16x32_bf16(pa2, vb1, c, 0, 0, 0);
        c = __builtin_amdgcn_mfma_f32_16x16x32_bf16(pa1, vb1, c, 0, 0, 0);
        accO[ni] = c;
      }
    }
    __syncthreads();
  }

  const int tqo = qt * 64 + w * 16 + lg * 4;
#pragma unroll
  for (int r = 0; r < 4; ++r) {
    const float inv = 1.0f / lrun[r];
#pragma unroll
    for (int ni = 0; ni < 4; ++ni)
      o[((size_t)(tqo + r) * 16 + h) * 64 + ni * 16 + lr] = accO[ni][r] * inv;
  }
}

// ---------- router: top-2 of softmax(h2 @ Wr) ----------
__global__ __launch_bounds__(64) void router_kernel(const float* __restrict__ h2,
                                                    const float* __restrict__ Wr,
                                                    int* __restrict__ eidx,
                                                    float* __restrict__ egate) {
  const int t = blockIdx.x;
  const int l = threadIdx.x;
  float p[8];
#pragma unroll
  for (int e = 0; e < 8; ++e) p[e] = 0.f;
  for (int d = l; d < 1024; d += 64) {
    const float x = h2[(size_t)t * 1024 + d];
    const float4 w0 = *reinterpret_cast<const float4*>(&Wr[d * 8]);
    const float4 w1 = *reinterpret_cast<const float4*>(&Wr[d * 8 + 4]);
    p[0] += x * w0.x; p[1] += x * w0.y; p[2] += x * w0.z; p[3] += x * w0.w;
    p[4] += x * w1.x; p[5] += x * w1.y; p[6] += x * w1.z; p[7] += x * w1.w;
  }
#pragma unroll
  for (int off = 32; off; off >>= 1) {
#pragma unroll
    for (int e = 0; e < 8; ++e) p[e] += __shfl_xor(p[e], off);
  }
  if (l == 0) {
    int i0 = 0; float b0 = p[0];
#pragma unroll
    for (int e = 1; e < 8; ++e) if (p[e] > b0) { b0 = p[e]; i0 = e; }
    int i1 = -1; float b1 = -INFINITY;
#pragma unroll
    for (int e = 0; e < 8; ++e) if (e != i0 && p[e] > b1) { b1 = p[e]; i1 = e; }
    const float ex = expf(b1 - b0);
    eidx[t * 2] = i0; eidx[t * 2 + 1] = i1;
    egate[t * 2] = 1.0f / (1.0f + ex);
    egate[t * 2 + 1] = ex / (1.0f + ex);
  }
}

// ---------- dispatch: replicate jnp cumsum slot assignment ----------
__global__ __launch_bounds__(256) void dispatch_kernel(
    const int* __restrict__ eidx, int* __restrict__ cnt,
    int* __restrict__ slot_token, int* __restrict__ entry_slot) {
  __shared__ unsigned char ef[2048];
  __shared__ unsigned short ch[256][8];
  const int tid = threadIdx.x;
  for (int i = tid; i < 2048; i += 256) ef[i] = (unsigned char)eidx[i];
  __syncthreads();
  int loc[8];
#pragma unroll
  for (int e = 0; e < 8; ++e) loc[e] = 0;
  const int base = tid * 8;
  for (int j = 0; j < 8; ++j) {
    const int ee = ef[base + j];
#pragma unroll
    for (int e = 0; e < 8; ++e) loc[e] += (ee == e);
  }
#pragma unroll
  for (int e = 0; e < 8; ++e) ch[tid][e] = (unsigned short)loc[e];
  __syncthreads();
  int pre[8];
#pragma unroll
  for (int e = 0; e < 8; ++e) pre[e] = 0;
  for (int t2 = 0; t2 < tid; ++t2) {
#pragma unroll
    for (int e = 0; e < 8; ++e) pre[e] += ch[t2][e];
  }
  if (tid == 255) {
#pragma unroll
    for (int e = 0; e < 8; ++e) cnt[e] = min(pre[e] + loc[e], 512);
  }
  for (int j = 0; j < 8; ++j) {
    const int i = base + j;
    const int ee = ef[i];
    int slot = 0;
#pragma unroll
    for (int e = 0; e < 8; ++e) {
      if (e == ee) { slot = pre[e]; pre[e] = pre[e] + 1; }
    }
    if (slot < 512) {
      slot_token[ee * 512 + slot] = i >> 1;
      entry_slot[i] = slot;
    } else {
      entry_slot[i] = -1;
    }
  }
}

// ---------- pre-convert dispatched tokens to bf16: xbf[e][slot][1024] ----------
__global__ __launch_bounds__(256) void moe_xbf_kernel(
    const float* __restrict__ h2, const int* __restrict__ cnt,
    const int* __restrict__ slot_token, unsigned short* __restrict__ xbf) {
  const int row = blockIdx.x;          // e*512 + slot
  const int e = row >> 9, slot = row & 511;
  const int tid = threadIdx.x;
  ushort4 o;
  if (slot < cnt[e]) {
    const int tok = slot_token[row];
    const float4 f = *reinterpret_cast<const float4*>(&h2[(size_t)tok * 1024 + tid * 4]);
    o = make_ushort4(bf16_rne(f.x), bf16_rne(f.y), bf16_rne(f.z), bf16_rne(f.w));
  } else {
    o = make_ushort4(0, 0, 0, 0);
  }
  *reinterpret_cast<ushort4*>(&xbf[(size_t)row * 1024 + tid * 4]) = o;
}

// ---------- MoE pass 1: act = silu(X@Wg)*(X@Wu) ----------
// grid 512 flat: e = bx&7 (expert->XCD), nt = bx>>3 (BN=32). BM=512 (whole expert).
// A read directly from global (xbf, zero-padded). Weights: dbuf LDS + 1-step reg prefetch.
__global__ __launch_bounds__(256, 2) void moe_mlp1_kernel(
    const unsigned short* __restrict__ xbf, const float* __restrict__ Wg,
    const float* __restrict__ Wu, const int* __restrict__ cnt,
    unsigned short* __restrict__ act) {
  const int bx = blockIdx.x;
  const int e = bx & 7, nt = bx >> 3;
  const int n0 = nt * 32;
  const int ce = cnt[e];
  if (ce <= 0) return;
  __shared__ alignas(16) unsigned short BgL[2][32][72], BuL[2][32][72];
  const int tid = threadIdx.x;
  const int w = tid >> 6, l = tid & 63;
  const int lr = l & 15, lg = l >> 4;
  const int wc = tid & 31, kq8 = tid >> 5;   // weight staging: col 0..31, k-octet 0..7
  const float* WgE = Wg + (size_t)e * 1024 * 2048 + (size_t)kq8 * 8 * 2048 + n0 + wc;
  const float* WuE = Wu + (size_t)e * 1024 * 2048 + (size_t)kq8 * 8 * 2048 + n0 + wc;
  const unsigned short* xbE = xbf + (size_t)e * 512 * 1024;

  f32x4 accG[8][2], accU[8][2];
#pragma unroll
  for (int mi = 0; mi < 8; ++mi)
#pragma unroll
    for (int ni = 0; ni < 2; ++ni) {
      accG[mi][ni] = (f32x4){0.f, 0.f, 0.f, 0.f};
      accU[mi][ni] = (f32x4){0.f, 0.f, 0.f, 0.f};
    }

  float wgr[8], wur[8];
  // prologue: stage W(0), issue W(1)
#pragma unroll
  for (int j = 0; j < 8; ++j) { wgr[j] = WgE[(size_t)j * 2048]; wur[j] = WuE[(size_t)j * 2048]; }
  {
    u16x8 g8, u8;
#pragma unroll
    for (int j = 0; j < 8; ++j) { g8[j] = bf16_rne(wgr[j]); u8[j] = bf16_rne(wur[j]); }
    *reinterpret_cast<u16x8*>(&BgL[0][wc][kq8 * 8]) = g8;
    *reinterpret_cast<u16x8*>(&BuL[0][wc][kq8 * 8]) = u8;
  }
#pragma unroll
  for (int j = 0; j < 8; ++j) { wgr[j] = WgE[(size_t)(64 + j) * 2048]; wur[j] = WuE[(size_t)(64 + j) * 2048]; }
  __syncthreads();

  for (int t = 0; t < 16; ++t) {
    const int cur = t & 1;
    bfrag bgf[2][2], buf2[2][2];
#pragma unroll
    for (int ni = 0; ni < 2; ++ni)
#pragma unroll
      for (int kf = 0; kf < 2; ++kf) {
        bgf[ni][kf]  = *reinterpret_cast<const bfrag*>(&BgL[cur][ni * 16 + lr][kf * 32 + lg * 8]);
        buf2[ni][kf] = *reinterpret_cast<const bfrag*>(&BuL[cur][ni * 16 + lr][kf * 32 + lg * 8]);
      }
    u16x8 g8, u8;
    if (t < 15) {
#pragma unroll
      for (int j = 0; j < 8; ++j) { g8[j] = bf16_rne(wgr[j]); u8[j] = bf16_rne(wur[j]); }
    }
    if (t < 14) {
      const size_t kb = (size_t)(t + 2) * 64;
#pragma unroll
      for (int j = 0; j < 8; ++j) { wgr[j] = WgE[(kb + j) * 2048]; wur[j] = WuE[(kb + j) * 2048]; }
    }
    const int kA = t * 64 + lg * 8;
#pragma unroll
    for (int mi = 0; mi < 8; ++mi) {
      const int row0 = (mi * 4 + w) * 16;   // wave-interleaved 16-row groups
      if (row0 < ce) {
        const unsigned short* ap = &xbE[(size_t)(row0 + lr) * 1024 + kA];
        const bfrag a0 = *reinterpret_cast<const bfrag*>(ap);
        const bfrag a1 = *reinterpret_cast<const bfrag*>(ap + 32);
#pragma unroll
        for (int ni = 0; ni < 2; ++ni) {
          accG[mi][ni] = __builtin_amdgcn_mfma_f32_16x16x32_bf16(a0, bgf[ni][0], accG[mi][ni], 0, 0, 0);
          accG[mi][ni] = __builtin_amdgcn_mfma_f32_16x16x32_bf16(a1, bgf[ni][1], accG[mi][ni], 0, 0, 0);
          accU[mi][ni] = __builtin_amdgcn_mfma_f32_16x16x32_bf16(a0, buf2[ni][0], accU[mi][ni], 0, 0, 0);
          accU[mi][ni] = __builtin_amdgcn_mfma_f32_16x16x32_bf16(a1, buf2[ni][1], accU[mi][ni], 0, 0, 0);
        }
      }
    }
    if (t < 15) {
      *reinterpret_cast<u16x8*>(&BgL[cur ^ 1][wc][kq8 * 8]) = g8;
      *reinterpret_cast<u16x8*>(&BuL[cur ^ 1][wc][kq8 * 8]) = u8;
    }
    __syncthreads();
  }
  // epilogue
#pragma unroll
  for (int mi = 0; mi < 8; ++mi) {
    const int row0 = (mi * 4 + w) * 16;
    if (row0 < ce) {
#pragma unroll
      for (int r = 0; r < 4; ++r) {
        const int m = row0 + lg * 4 + r;
        if (m < ce) {
#pragma unroll
          for (int ni = 0; ni < 2; ++ni) {
            const float gg = accG[mi][ni][r];
            const float uu = accU[mi][ni][r];
            const float a = gg / (1.0f + __expf(-gg)) * uu;
            act[((size_t)e * 512 + m) * 2048 + n0 + ni * 16 + lr] = bf16_rne(a);
          }
        }
      }
    }
  }
}

// ---------- MoE pass 2 (split-K=2): ob_part = act @ Wd ----------
// grid 512 flat: e = bx&7, nt = (bx>>3)&31, kc = bx>>8. BM=512, BN=32, K-slice 1024.
__global__ __launch_bounds__(256, 2) void moe_mlp2_kernel(
    const unsigned short* __restrict__ act, const float* __restrict__ Wd,
    const int* __restrict__ cnt, float* __restrict__ ob) {
  const int bx = blockIdx.x;
  const int e = bx & 7;
  const int rr = bx >> 3;
  const int nt = rr & 31, kc = rr >> 5;
  const int n0 = nt * 32;
  const int ce = cnt[e];
  if (ce <= 0) return;
  __shared__ alignas(16) unsigned short BsL[2][32][72];
  const int tid = threadIdx.x;
  const int w = tid >> 6, l = tid & 63;
  const int lr = l & 15, lg = l >> 4;
  const int wc = tid & 31, kq8 = tid >> 5;
  const unsigned short* actE = act + (size_t)e * 512 * 2048 + (size_t)kc * 1024;
  const float* WdE = Wd + (size_t)e * 2048 * 1024 + (size_t)(kc * 1024 + kq8 * 8) * 1024 + n0 + wc;
  float* obE = ob + (size_t)kc * 8 * 512 * 1024;

  f32x4 acc[8][2];
#pragma unroll
  for (int mi = 0; mi < 8; ++mi)
#pragma unroll
    for (int ni = 0; ni < 2; ++ni) acc[mi][ni] = (f32x4){0.f, 0.f, 0.f, 0.f};

  float wdr[8];
#pragma unroll
  for (int j = 0; j < 8; ++j) wdr[j] = WdE[(size_t)j * 1024];
  {
    u16x8 d8;
#pragma unroll
    for (int j = 0; j < 8; ++j) d8[j] = bf16_rne(wdr[j]);
    *reinterpret_cast<u16x8*>(&BsL[0][wc][kq8 * 8]) = d8;
  }
#pragma unroll
  for (int j = 0; j < 8; ++j) wdr[j] = WdE[(size_t)(64 + j) * 1024];
  __syncthreads();

  for (int t = 0; t < 16; ++t) {
    const int cur = t & 1;
    bfrag bf2[2][2];
#pragma unroll
    for (int ni = 0; ni < 2; ++ni)
#pragma unroll
      for (int kf = 0; kf < 2; ++kf)
        bf2[ni][kf] = *reinterpret_cast<const bfrag*>(&BsL[cur][ni * 16 + lr][kf * 32 + lg * 8]);
    u16x8 d8;
    if (t < 15) {
#pragma unroll
      for (int j = 0; j < 8; ++j) d8[j] = bf16_rne(wdr[j]);
    }
    if (t < 14) {
      const size_t kb = (size_t)(t + 2) * 64;
#pragma unroll
      for (int j = 0; j < 8; ++j) wdr[j] = WdE[(kb + j) * 1024];
    }
    const int kA = t * 64 + lg * 8;
#pragma unroll
    for (int mi = 0; mi < 8; ++mi) {
      const int row0 = (mi * 4 + w) * 16;
      if (row0 < ce) {
        const unsigned short* ap = &actE[(size_t)(row0 + lr) * 2048 + kA];
        const bfrag a0 = *reinterpret_cast<const bfrag*>(ap);
        const bfrag a1 = *reinterpret_cast<const bfrag*>(ap + 32);
#pragma unroll
        for (int ni = 0; ni < 2; ++ni) {
          acc[mi][ni] = __builtin_amdgcn_mfma_f32_16x16x32_bf16(a0, bf2[ni][0], acc[mi][ni], 0, 0, 0);
          acc[mi][ni] = __builtin_amdgcn_mfma_f32_16x16x32_bf16(a1, bf2[ni][1], acc[mi][ni], 0, 0, 0);
        }
      }
    }
    if (t < 15) {
      *reinterpret_cast<u16x8*>(&BsL[cur ^ 1][wc][kq8 * 8]) = d8;
    }
    __syncthreads();
  }
#pragma unroll
  for (int mi = 0; mi < 8; ++mi) {
    const int row0 = (mi * 4 + w) * 16;
    if (row0 < ce) {
#pragma unroll
      for (int r = 0; r < 4; ++r) {
        const int m = row0 + lg * 4 + r;
        if (m < ce) {
#pragma unroll
          for (int ni = 0; ni < 2; ++ni)
            obE[((size_t)e * 512 + m) * 1024 + n0 + ni * 16 + lr] = acc[mi][ni][r];
        }
      }
    }
  }
}

// ---------- combine: out += sum_k gate * (ob0+ob1)[e_k][slot_k] ----------
__global__ __launch_bounds__(256) void combine_kernel(
    const float* __restrict__ ob, const int* __restrict__ eidx,
    const float* __restrict__ egate, const int* __restrict__ entry_slot,
    float* __restrict__ out) {
  const int t = blockIdx.x;
  const int d = threadIdx.x * 4;
  const size_t half = (size_t)8 * 512 * 1024;
  float4 o4 = *reinterpret_cast<float4*>(&out[(size_t)t * 1024 + d]);
#pragma unroll
  for (int kk = 0; kk < 2; ++kk) {
    const int i = t * 2 + kk;
    const int s = entry_slot[i];
    if (s >= 0) {
      const int e = eidx[i];
      const float g = egate[i];
      const size_t base = ((size_t)e * 512 + s) * 1024 + d;
      const float4 c0 = *reinterpret_cast<const float4*>(&ob[base]);
      const float4 c1 = *reinterpret_cast<const float4*>(&ob[half + base]);
      o4.x += g * (c0.x + c1.x); o4.y += g * (c0.y + c1.y);
      o4.z += g * (c0.z + c1.z); o4.w += g * (c0.w + c1.w);
    }
  }
  *reinterpret_cast<float4*>(&out[(size_t)t * 1024 + d]) = o4;
}

extern "C" void kernel_launch(void* const* d_in, const int* in_sizes, int n_in,
                              void* d_out, int out_size, void* d_ws, size_t ws_size,
                              hipStream_t stream) {
  const float* hidden = (const float*)d_in[0];
  const int* posids  = (const int*)d_in[1];
  const float* ln1w  = (const float*)d_in[2];
  const float* ln2w  = (const float*)d_in[3];
  const float* Wq    = (const float*)d_in[4];
  const float* Wk    = (const float*)d_in[5];
  const float* Wv    = (const float*)d_in[6];
  const float* Wo    = (const float*)d_in[7];
  const float* Wr    = (const float*)d_in[8];
  const float* Wg    = (const float*)d_in[9];
  const float* Wu    = (const float*)d_in[10];
  const float* Wd    = (const float*)d_in[11];
  float* out = (float*)d_out;

  char* p = (char*)d_ws;
  auto alloc = [&](size_t bytes) { char* r = p; p += (bytes + 255) & ~(size_t)255; return r; };
  float* h1   = (float*)alloc((size_t)1024 * 1024 * 4);
  float* qb   = (float*)alloc((size_t)1024 * 1024 * 4);
  float* kb   = (float*)alloc((size_t)1024 * 256 * 4);
  float* vb   = (float*)alloc((size_t)1024 * 256 * 4);
  float* ao   = (float*)alloc((size_t)1024 * 1024 * 4);
  float* h2   = (float*)alloc((size_t)1024 * 1024 * 4);
  unsigned short* act = (unsigned short*)alloc((size_t)8 * 512 * 2048 * 2);
  float* obuf = (float*)alloc((size_t)2 * 8 * 512 * 1024 * 4);
  int* eidx   = (int*)alloc(2048 * 4);
  float* egate = (float*)alloc(2048 * 4);
  int* cnt    = (int*)alloc(8 * 4);
  int* slot_token = (int*)alloc((size_t)8 * 512 * 4);
  int* entry_slot = (int*)alloc(2048 * 4);
  float* cosT = (float*)alloc((size_t)1024 * 32 * 4);
  float* sinT = (float*)alloc((size_t)1024 * 32 * 4);
  unsigned short* Kp1 = (unsigned short*)alloc((size_t)4 * 1024 * 64 * 2);
  unsigned short* Kp2 = (unsigned short*)alloc((size_t)4 * 1024 * 64 * 2);
  unsigned short* Vp1 = (unsigned short*)alloc((size_t)4 * 1024 * 64 * 2);
  unsigned short* Vp2 = (unsigned short*)alloc((size_t)4 * 1024 * 64 * 2);
  unsigned short* xbf = (unsigned short*)alloc((size_t)8 * 512 * 1024 * 2);

  rope_table_kernel<<<128, 256, 0, stream>>>(posids, cosT, sinT);
  ln_kernel<<<1024, 256, 0, stream>>>(hidden, ln1w, h1);
  gemm_split3_kernel<<<dim3(16, 16), 256, 0, stream>>>(h1, Wq, qb, nullptr, 1024, 1024, 1);
  gemm_split3_kernel<<<dim3(16, 4), 256, 0, stream>>>(h1, Wk, kb, nullptr, 256, 1024, 1);
  gemm_split3_kernel<<<dim3(16, 4), 256, 0, stream>>>(h1, Wv, vb, nullptr, 256, 1024, 1);
  rope_kernel<<<dim3(1024, 20), 32, 0, stream>>>(qb, kb, cosT, sinT);
  prep_kv_kernel<<<1024, 256, 0, stream>>>(kb, vb, Kp1, Kp2, Vp1, Vp2);
  attn_kernel<<<dim3(16, 16), 256, 0, stream>>>(qb, Kp1, Kp2, Vp1, Vp2, ao);
  gemm_split3_kernel<<<dim3(16, 16), 256, 0, stream>>>(ao, Wo, out, hidden, 1024, 1024, 0);
  ln_kernel<<<1024, 256, 0, stream>>>(out, ln2w, h2);
  router_kernel<<<1024, 64, 0, stream>>>(h2, Wr, eidx, egate);
  dispatch_kernel<<<1, 256, 0, stream>>>(eidx, cnt, slot_token, entry_slot);
  moe_xbf_kernel<<<4096, 256, 0, stream>>>(h2, cnt, slot_token, xbf);
  moe_mlp1_kernel<<<512, 256, 0, stream>>>(xbf, Wg, Wu, cnt, act);
  moe_mlp2_kernel<<<512, 256, 0, stream>>>(act, Wd, cnt, obuf);
  combine_kernel<<<1024, 256, 0, stream>>>(obuf, eidx, egate, entry_slot, out);
}